// Round 3
// baseline (460.895 us; speedup 1.0000x reference)
//
#include <hip/hip_runtime.h>
#include <stdint.h>

#define DEVINL __device__ __forceinline__

typedef __attribute__((ext_vector_type(8))) __bf16 bf16x8;
typedef __attribute__((ext_vector_type(8))) short s16x8;
typedef __attribute__((ext_vector_type(4))) float f32x4;

constexpr int NN = 5000;   // nodes
constexpr int NE = 10000;  // edges
constexpr int NG = 200;    // graphs
constexpr int BM = 128;
constexpr int MBLK = (NE + BM - 1) / BM;  // 79
constexpr int EROWS = MBLK * BM;          // 10112
constexpr int KSPLIT = 2;
constexpr int NKP = 36;                   // padded k count (33 real: 32 + bias)
constexpr int PERK = NKP / KSPLIT;        // 18 k's per block

constexpr int cgcd(int a, int b) { return b == 0 ? a : cgcd(b, a % b); }

DEVINL short f2bf(float f) {  // RNE fp32->bf16
  union { float f; unsigned u; } v; v.f = f;
  unsigned u = v.u + 0x7fffu + ((v.u >> 16) & 1u);
  return (short)(u >> 16);
}

DEVINL float bf2f(unsigned short s) {
  union { unsigned u; float f; } v; v.u = ((unsigned)s) << 16;
  return v.f;
}

DEVINL void gload16(const void* g, void* l) {
  __builtin_amdgcn_global_load_lds(
      (const __attribute__((address_space(1))) void*)g,
      (__attribute__((address_space(3))) void*)l, 16, 0, 0);
}

// ---------------- small kernels ----------------

__global__ void count_edges(const int* dst, float* cnt) {
  int e = blockIdx.x * 256 + threadIdx.x;
  if (e < NE) atomicAdd(&cnt[dst[e]], 1.0f);
}

__global__ void count_graphs(const int* batch, float* gcnt) {
  int n = blockIdx.x * 256 + threadIdx.x;
  if (n < NN) atomicAdd(&gcnt[batch[n]], 1.0f);
}

// exclusive scan of node edge-counts -> noff; zeroes fill
__global__ void node_scan(const float* cnt, int* noff, int* fill) {
  __shared__ int s[1024];
  __shared__ int carry;
  int t = threadIdx.x;
  if (t == 0) carry = 0;
  __syncthreads();
  for (int c0 = 0; c0 < NN; c0 += 1024) {
    int i = c0 + t;
    int v = (i < NN) ? (int)cnt[i] : 0;
    s[t] = v;
    __syncthreads();
    for (int d = 1; d < 1024; d <<= 1) {
      int u = (t >= d) ? s[t - d] : 0;
      __syncthreads();
      s[t] += u;
      __syncthreads();
    }
    if (i < NN) { noff[i] = carry + s[t] - v; fill[i] = 0; }
    __syncthreads();
    if (t == 0) carry += s[1023];
    __syncthreads();
  }
}

__global__ void csr_fill(const int* dst, const int* noff, int* fill, int* elist) {
  int e = blockIdx.x * 256 + threadIdx.x;
  if (e < NE) {
    int n = dst[e];
    int p = noff[n] + atomicAdd(&fill[n], 1);
    elist[p] = e;
  }
}

__global__ void cast_x0(const float* x0, short* xbf0) {
  int idx = blockIdx.x * 256 + threadIdx.x;  // n*32+i
  if (idx >= NN * 32) return;
  int n = idx >> 5, i = idx & 31;
  xbf0[idx] = (i < 15) ? f2bf(x0[n * 15 + i]) : (short)0;
}

// h = relu(edge_attr @ w1 + b1)   [E,3]@[3,32]
__global__ void edge_mlp(const float* ea, const float* w1, const float* b1, float* h) {
  __shared__ float w1s[96];
  __shared__ float b1s[32];
  int t = threadIdx.x;
  if (t < 96) w1s[t] = w1[t];
  if (t < 32) b1s[t] = b1[t];
  __syncthreads();
  int e = blockIdx.x * 8 + (t >> 5);
  int k = t & 31;
  if (e < NE) {
    float a0 = ea[e * 3 + 0], a1 = ea[e * 3 + 1], a2 = ea[e * 3 + 2];
    float v = b1s[k] + a0 * w1s[k] + a1 * w1s[32 + k] + a2 * w1s[64 + k];
    h[e * 32 + k] = v > 0.f ? v : 0.f;
  }
}

// B panel: Bp[kt][n][kk] bf16 (kt = 32-wide K-step), 16B chunks XOR-swizzled
// by ((n>>1)&3).  kap = kt*32+kk = k*DIN_PAD + i;  k in [0,NKP): k<32 = w2,
// k==32 = b2 (bias), k>32 zero pad; i>=DIN_DATA zero pad.
template <int DIN_DATA, int DIN_PAD, int DOUT>
__global__ void build_B(const float* w2, const float* b2, short* Bp) {
  constexpr int KTOT = NKP * DIN_PAD;
  constexpr int TOTC = (KTOT / 8) * DOUT;
  int idx = blockIdx.x * 256 + threadIdx.x;
  if (idx >= TOTC) return;
  int cc = idx & 3;
  int n = (idx >> 2) % DOUT;
  int kt = (idx >> 2) / DOUT;
  int kap0 = kt * 32 + cc * 8;
  s16x8 v;
#pragma unroll
  for (int j = 0; j < 8; ++j) {
    int kap = kap0 + j;
    int k = kap / DIN_PAD, i = kap % DIN_PAD;
    float val = 0.f;
    if (i < DIN_DATA && k <= 32)
      val = (k < 32) ? w2[(size_t)(k * DIN_DATA + i) * DOUT + n]
                     : b2[(size_t)i * DOUT + n];
    v[j] = f2bf(val);
  }
  int swz = cc ^ ((n >> 1) & 3);
  *(s16x8*)((char*)Bp + (size_t)kt * DOUT * 64 + n * 64 + swz * 16) = v;
}

// Fused gather + rank-structured GEMM; writes per-edge partial msg tiles
// (plain coalesced stores, no atomics):
//   P[by][e][o] (+)= sum_{k in block range} h~[e,k] * (x[src[e]] @ B_k)[o]
template <int DIN_PAD, int DOUT, int PHASE_KT>
__launch_bounds__(512, 2)
__global__ void fused_gemm(const short* xbf, const float* hedge, const short* Bp,
                           const int* srcI, float* Pout) {
  constexpr int NI = DIN_PAD / 32;       // K-steps per k
  constexpr int ROWB = DIN_PAD * 2;      // bytes per xg row
  constexpr int CHPR = ROWB / 16;        // 16B chunks per row
  constexpr int CHLOG = (CHPR == 4) ? 2 : (CHPR == 8) ? 3 : 4;
  constexpr int SWZM = (CHPR >= 8) ? 7 : 3;
  constexpr int NT = DOUT / 64;          // 16-col frags per wave (8 waves 2Mx4N)
  constexpr int MT = 4;                  // wave covers 64 rows
  constexpr int KT_TOTAL = PERK * NI;
  constexpr int NPH = KT_TOTAL / PHASE_KT;
  constexpr int UNR = PHASE_KT * NI / cgcd(PHASE_KT, NI);  // LCM
  constexpr int NSUP = KT_TOTAL / UNR;
  constexpr int PPS = UNR / PHASE_KT;    // phases per super-iter
  constexpr int PHB = PHASE_KT * DOUT * 64;  // bytes per phase buffer
  constexpr int XGB = BM * ROWB;
  constexpr int SMB = (XGB > 2 * PHB) ? XGB : 2 * PHB;

  __shared__ __align__(16) char smem[SMB];   // union: xg (gather) then B dbuf
  __shared__ __align__(16) short hs[PERK * BM];
  __shared__ int src_s[BM];

  const int t = threadIdx.x, lane = t & 63, w = t >> 6;
  const int wm = w >> 2, wn = w & 3;
  const int m0 = blockIdx.x * BM;
  if (t < BM) {
    int e = m0 + t;
    src_s[t] = (e < NE) ? srcI[e] : 0;
  }
  __syncthreads();

  // ---- gather xg (LDS linear dest, swizzle folded into per-lane source) ----
  constexpr int XCH = BM * CHPR;
#pragma unroll
  for (int rd = 0; rd < XCH / 512; ++rd) {
    int L = rd * 512 + w * 64 + lane;
    int r = L >> CHLOG, pch = L & (CHPR - 1);
    int j = pch ^ (r & SWZM);
    gload16((const char*)xbf + (size_t)src_s[r] * ROWB + j * 16,
            (char*)smem + (size_t)(rd * 512 + w * 64) * 16);
  }
  // h transpose-load for this block's k-range: hs[kl][r]
  const int k0 = blockIdx.y * PERK;
  for (int idx = t; idx < PERK * BM; idx += 512) {
    int kl = idx >> 7, r = idx & 127;
    int kg = k0 + kl;
    int e = m0 + r;
    float v = 0.f;
    if (e < NE) v = (kg < 32) ? hedge[e * 32 + kg] : (kg == 32 ? 1.0f : 0.f);
    hs[idx] = f2bf(v);
  }
  __syncthreads();

  // ---- hoist A fragments, then xg LDS is dead (reused for B buffers) ----
  bf16x8 afr[NI][MT];
#pragma unroll
  for (int ii = 0; ii < NI; ++ii)
#pragma unroll
    for (int mt = 0; mt < MT; ++mt) {
      int r = wm * 64 + mt * 16 + (lane & 15);
      int c = ii * 4 + (lane >> 4);
      int pos = c ^ (r & SWZM);
      afr[ii][mt] = *(const bf16x8*)((const char*)smem + r * ROWB + pos * 16);
    }
  __syncthreads();  // all waves done reading xg before B staging overwrites

  const char* Bg = (const char*)Bp + (size_t)(k0 * NI) * (DOUT * 64);
  auto stageB = [&](int ph, int buf) {
    const char* srcB = Bg + (size_t)ph * PHB;
    char* dstB = (char*)smem + buf * PHB;
    constexpr int CH = PHB / 16;  // 16B chunks
#pragma unroll
    for (int cc = 0; cc < (CH + 511) / 512; ++cc) {
      int base = cc * 512 + w * 64;
      if (base < CH)
        gload16(srcB + (size_t)(base + lane) * 16, dstB + (size_t)base * 16);
    }
  };

  f32x4 msg[MT][NT], part[MT][NT];
#pragma unroll
  for (int mt = 0; mt < MT; ++mt)
#pragma unroll
    for (int nt = 0; nt < NT; ++nt)
#pragma unroll
      for (int i = 0; i < 4; ++i) { msg[mt][nt][i] = 0.f; part[mt][nt][i] = 0.f; }

  stageB(0, 0);
  __syncthreads();
  int cur = 0;
  for (int sp = 0; sp < NSUP; ++sp) {
#pragma unroll
    for (int j = 0; j < UNR; ++j) {
      if ((j % PHASE_KT) == 0) {  // prefetch next phase into other buffer
        int ph = sp * PPS + j / PHASE_KT;
        if (ph + 1 < NPH) stageB(ph + 1, cur ^ 1);
      }
      const int kt = sp * UNR + j;
      constexpr int NIL = NI;  // for % folding
      bf16x8 bfr[NT];
#pragma unroll
      for (int nt = 0; nt < NT; ++nt) {
        int n = wn * (DOUT / 4) + nt * 16 + (lane & 15);
        int cch = (lane >> 4) ^ ((n >> 1) & 3);
        bfr[nt] = *(const bf16x8*)((const char*)smem + cur * PHB +
                                   (j % PHASE_KT) * (DOUT * 64) + n * 64 + cch * 16);
      }
#pragma unroll
      for (int mt = 0; mt < MT; ++mt)
#pragma unroll
        for (int nt = 0; nt < NT; ++nt)
          part[mt][nt] = __builtin_amdgcn_mfma_f32_16x16x32_bf16(
              afr[j % NIL][mt], bfr[nt], part[mt][nt], 0, 0, 0);
      if ((j % NIL) == NIL - 1) {  // k boundary: rescale by h[r,k]
        int kl = kt / NIL;
#pragma unroll
        for (int mt = 0; mt < MT; ++mt) {
          int rb = wm * 64 + mt * 16 + (lane >> 4) * 4;
          ushort4 hv = *(const ushort4*)((const char*)hs + (size_t)(kl * BM + rb) * 2);
          float h0 = bf2f(hv.x), h1 = bf2f(hv.y), h2 = bf2f(hv.z), h3 = bf2f(hv.w);
#pragma unroll
          for (int nt = 0; nt < NT; ++nt) {
            msg[mt][nt][0] += h0 * part[mt][nt][0];
            msg[mt][nt][1] += h1 * part[mt][nt][1];
            msg[mt][nt][2] += h2 * part[mt][nt][2];
            msg[mt][nt][3] += h3 * part[mt][nt][3];
#pragma unroll
            for (int i = 0; i < 4; ++i) part[mt][nt][i] = 0.f;
          }
        }
      }
      if ((j % PHASE_KT) == PHASE_KT - 1) {
        __syncthreads();
        cur ^= 1;
      }
    }
  }
  // ---- epilogue: plain coalesced stores of the partial tile ----
  float* P = Pout + ((size_t)blockIdx.y * EROWS + m0) * DOUT;
#pragma unroll
  for (int mt = 0; mt < MT; ++mt)
#pragma unroll
    for (int nt = 0; nt < NT; ++nt) {
      int col = wn * (DOUT / 4) + nt * 16 + (lane & 15);
#pragma unroll
      for (int reg = 0; reg < 4; ++reg) {
        int r = wm * 64 + mt * 16 + (lane >> 4) * 4 + reg;
        P[(size_t)r * DOUT + col] = msg[mt][nt][reg];
      }
    }
}

// out = gather-mean(P via CSR) + x@root + bias -> BN -> ReLU (+ bf16 copy)
template <int DIN, int DOUT>
__global__ void post_bn(const float* P, const float* cnt, const int* noff,
                        const int* elist, const float* xin, const float* root,
                        const float* bias, const float* bg, const float* bb,
                        const float* bm, const float* bv, float* xout, short* xbf) {
  constexpr int TN = 16;
  constexpr int OSPLIT = 256 / DOUT;
  __shared__ float xs[TN * DIN];
  __shared__ int es_off[TN];
  __shared__ int es_cnt[TN];
  int n0 = blockIdx.x * TN;
  int t = threadIdx.x;
  if (t < TN) {
    int n = n0 + t;
    es_off[t] = (n < NN) ? noff[n] : 0;
    es_cnt[t] = (n < NN) ? (int)cnt[n] : 0;
  }
  for (int idx = t; idx < TN * DIN; idx += 256) {
    int nn = idx / DIN, ii = idx % DIN;
    int n = n0 + nn;
    xs[idx] = (n < NN) ? xin[(size_t)n * DIN + ii] : 0.f;
  }
  __syncthreads();
  int o = t % DOUT;
  int ng = t / DOUT;
  float scale = bg[o] * rsqrtf(bv[o] + 1e-5f);
  float mo = bm[o], bo = bb[o], bi = bias[o];
  for (int nn = ng; nn < TN; nn += OSPLIT) {
    int n = n0 + nn;
    if (n >= NN) break;
    int off = es_off[nn], c = es_cnt[nn];
    float s = 0.f;
    for (int j = 0; j < c; ++j) {
      int e = elist[off + j];
      s += P[(size_t)e * DOUT + o] + P[(size_t)(EROWS + e) * DOUT + o];
    }
    float a = s / fmaxf((float)c, 1.f);
    float accv = a + bi;
#pragma unroll 8
    for (int i = 0; i < DIN; ++i) accv += xs[nn * DIN + i] * root[(size_t)i * DOUT + o];
    float v = (accv - mo) * scale + bo;
    v = v > 0.f ? v : 0.f;
    xout[(size_t)n * DOUT + o] = v;
    if (xbf) xbf[(size_t)n * DOUT + o] = f2bf(v);
  }
}

// parallel exclusive scan of per-graph counts (200 elems, one block)
__global__ void scan_offsets(const float* gcnt, const int* atom, int* goff, int* gidx) {
  __shared__ int s[256];
  int t = threadIdx.x;
  int c = (t < NG) ? (int)gcnt[t] : 0;
  s[t] = c;
  __syncthreads();
  for (int d = 1; d < 256; d <<= 1) {
    int v = (t >= d) ? s[t - d] : 0;
    __syncthreads();
    s[t] += v;
    __syncthreads();
  }
  if (t < NG) {
    int off = s[t] - c;
    goff[t] = off;
    int id = off + atom[t];
    gidx[t] = id < 0 ? 0 : (id > NN - 1 ? NN - 1 : id);  // JAX gather clamp
  }
}

__global__ void pool_kernel(const float* x3, const float* gcnt, const int* goff,
                            const int* gidx, float* hnew, float* ne_out) {
  int g = blockIdx.x, o = threadIdx.x;
  int st = goff[g];
  int cn = (int)gcnt[g];
  float s = 0.f;
  for (int n = st; n < st + cn; ++n) s += x3[(size_t)n * 256 + o];
  float ge = s / fmaxf(gcnt[g], 1.f);
  float ne = x3[(size_t)gidx[g] * 256 + o];
  ne_out[g * 256 + o] = ne;
  hnew[g * 256 + o] = 0.5f * ge + ne;
}

__global__ void final_mlp(const float* hnew, const float* mw, const float* mb, float* out) {
  __shared__ float hs[256];
  int g = blockIdx.x, j = threadIdx.x;
  hs[j] = hnew[g * 256 + j];
  __syncthreads();
  if (j < 200) {
    float accv = mb[j];
#pragma unroll 8
    for (int o = 0; o < 256; ++o) accv += hs[o] * mw[(size_t)o * 200 + j];
    out[g * 200 + j] = accv;
  }
}

// ---------------- host side ----------------

template <int DIN_DATA, int DIN_PAD, int DOUT, int PHASE_KT>
static void run_layer(void* const* d_in, int l, const float* ea, const int* srcI,
                      const short* xbf_in, const float* xin_f32, float* xout,
                      short* xbf_out, float* Pbuf, const float* cnt, const int* noff,
                      const int* elist, float* hedge, short* Bp, hipStream_t stream) {
  int base = 5 + (l - 1) * 10;
  const float* w1 = (const float*)d_in[base + 0];
  const float* b1 = (const float*)d_in[base + 1];
  const float* w2 = (const float*)d_in[base + 2];
  const float* b2 = (const float*)d_in[base + 3];
  const float* root = (const float*)d_in[base + 4];
  const float* bias = (const float*)d_in[base + 5];
  const float* bg = (const float*)d_in[base + 6];
  const float* bb = (const float*)d_in[base + 7];
  const float* bm = (const float*)d_in[base + 8];
  const float* bv = (const float*)d_in[base + 9];

  edge_mlp<<<(NE + 7) / 8, 256, 0, stream>>>(ea, w1, b1, hedge);
  constexpr int KTOT = NKP * DIN_PAD;
  build_B<DIN_DATA, DIN_PAD, DOUT>
      <<<((KTOT / 8) * DOUT + 255) / 256, 256, 0, stream>>>(w2, b2, Bp);
  fused_gemm<DIN_PAD, DOUT, PHASE_KT>
      <<<dim3(MBLK, KSPLIT), 512, 0, stream>>>(xbf_in, hedge, Bp, srcI, Pbuf);
  post_bn<DIN_DATA, DOUT><<<(NN + 15) / 16, 256, 0, stream>>>(
      Pbuf, cnt, noff, elist, xin_f32, root, bias, bg, bb, bm, bv, xout, xbf_out);
}

extern "C" void kernel_launch(void* const* d_in, const int* in_sizes, int n_in,
                              void* d_out, int out_size, void* d_ws, size_t ws_size,
                              hipStream_t stream) {
  const float* x0 = (const float*)d_in[0];
  const float* ea = (const float*)d_in[1];
  const int* eidx = (const int*)d_in[2];
  const int* batch = (const int*)d_in[3];
  const int* atom = (const int*)d_in[4];
  const float* mw = (const float*)d_in[35];
  const float* mb = (const float*)d_in[36];
  const int* srcI = eidx;
  const int* dstI = eidx + NE;
  float* out = (float*)d_out;

  char* p = (char*)d_ws;
  auto alloc = [&](size_t bytes) {
    char* r = p;
    p += (bytes + 255) & ~size_t(255);
    return r;
  };
  float* xA = (float*)alloc((size_t)NN * 256 * 4);
  float* xB = (float*)alloc((size_t)NN * 256 * 4);
  float* Pbuf = (float*)alloc((size_t)KSPLIT * EROWS * 256 * 4);
  float* cnt = (float*)alloc(NN * 4);
  int* noff = (int*)alloc(NN * 4);
  int* fill = (int*)alloc(NN * 4);
  int* elist = (int*)alloc(NE * 4);
  float* gcnt = (float*)alloc(NG * 4);
  int* goff = (int*)alloc(NG * 4);
  int* gidx = (int*)alloc(NG * 4);
  float* hnew = (float*)alloc((size_t)NG * 256 * 4);
  float* hedge = (float*)alloc((size_t)NE * 32 * 4);
  short* Bp = (short*)alloc((size_t)NKP * 128 * 256 * 2);
  short* xbf0 = (short*)alloc((size_t)NN * 32 * 2);
  short* xbfA = (short*)alloc((size_t)NN * 64 * 2);
  short* xbfB = (short*)alloc((size_t)NN * 128 * 2);

  hipMemsetAsync(cnt, 0, NN * 4, stream);
  hipMemsetAsync(gcnt, 0, NG * 4, stream);
  count_edges<<<(NE + 255) / 256, 256, 0, stream>>>(dstI, cnt);
  count_graphs<<<(NN + 255) / 256, 256, 0, stream>>>(batch, gcnt);
  node_scan<<<1, 1024, 0, stream>>>(cnt, noff, fill);
  csr_fill<<<(NE + 255) / 256, 256, 0, stream>>>(dstI, noff, fill, elist);
  cast_x0<<<(NN * 32 + 255) / 256, 256, 0, stream>>>(x0, xbf0);

  run_layer<15, 32, 64, 3>(d_in, 1, ea, srcI, xbf0, x0, xA, xbfA, Pbuf, cnt, noff,
                           elist, hedge, Bp, stream);
  run_layer<64, 64, 128, 3>(d_in, 2, ea, srcI, xbfA, xA, xB, xbfB, Pbuf, cnt, noff,
                            elist, hedge, Bp, stream);
  run_layer<128, 128, 256, 2>(d_in, 3, ea, srcI, xbfB, xB, xA, (short*)nullptr, Pbuf,
                              cnt, noff, elist, hedge, Bp, stream);

  scan_offsets<<<1, 256, 0, stream>>>(gcnt, atom, goff, gidx);
  pool_kernel<<<NG, 256, 0, stream>>>(xA, gcnt, goff, gidx, hnew, out + 40000);
  final_mlp<<<NG, 256, 0, stream>>>(hnew, mw, mb, out);
}

// Round 4
// 422.567 us; speedup vs baseline: 1.0907x; 1.0907x over previous
//
#include <hip/hip_runtime.h>
#include <stdint.h>

#define DEVINL __device__ __forceinline__

typedef __attribute__((ext_vector_type(8))) __bf16 bf16x8;
typedef __attribute__((ext_vector_type(8))) short s16x8;
typedef __attribute__((ext_vector_type(4))) float f32x4;

constexpr int NN = 5000;   // nodes
constexpr int NE = 10000;  // edges
constexpr int NG = 200;    // graphs
constexpr int BMT = 64;                     // edge rows per block
constexpr int MBLK = (NE + BMT - 1) / BMT;  // 157
constexpr int EROWS = MBLK * BMT;           // 10048
constexpr int NKP = 36;                     // padded k count (33 real: 32 + bias)

constexpr int cgcd(int a, int b) { return b == 0 ? a : cgcd(b, a % b); }

DEVINL short f2bf(float f) {  // RNE fp32->bf16
  union { float f; unsigned u; } v; v.f = f;
  unsigned u = v.u + 0x7fffu + ((v.u >> 16) & 1u);
  return (short)(u >> 16);
}

DEVINL float bf2f(unsigned short s) {
  union { unsigned u; float f; } v; v.u = ((unsigned)s) << 16;
  return v.f;
}

DEVINL void gload16(const void* g, void* l) {
  __builtin_amdgcn_global_load_lds(
      (const __attribute__((address_space(1))) void*)g,
      (__attribute__((address_space(3))) void*)l, 16, 0, 0);
}

// ---------------- small kernels ----------------

__global__ void count_edges(const int* dst, float* cnt) {
  int e = blockIdx.x * 256 + threadIdx.x;
  if (e < NE) atomicAdd(&cnt[dst[e]], 1.0f);
}

__global__ void count_graphs(const int* batch, float* gcnt) {
  int n = blockIdx.x * 256 + threadIdx.x;
  if (n < NN) atomicAdd(&gcnt[batch[n]], 1.0f);
}

// exclusive scan of node edge-counts -> noff; zeroes fill
__global__ void node_scan(const float* cnt, int* noff, int* fill) {
  __shared__ int s[1024];
  __shared__ int carry;
  int t = threadIdx.x;
  if (t == 0) carry = 0;
  __syncthreads();
  for (int c0 = 0; c0 < NN; c0 += 1024) {
    int i = c0 + t;
    int v = (i < NN) ? (int)cnt[i] : 0;
    s[t] = v;
    __syncthreads();
    for (int d = 1; d < 1024; d <<= 1) {
      int u = (t >= d) ? s[t - d] : 0;
      __syncthreads();
      s[t] += u;
      __syncthreads();
    }
    if (i < NN) { noff[i] = carry + s[t] - v; fill[i] = 0; }
    __syncthreads();
    if (t == 0) carry += s[1023];
    __syncthreads();
  }
}

__global__ void csr_fill(const int* dst, const int* noff, int* fill, int* elist) {
  int e = blockIdx.x * 256 + threadIdx.x;
  if (e < NE) {
    int n = dst[e];
    int p = noff[n] + atomicAdd(&fill[n], 1);
    elist[p] = e;
  }
}

__global__ void cast_x0(const float* x0, short* xbf0) {
  int idx = blockIdx.x * 256 + threadIdx.x;  // n*32+i
  if (idx >= NN * 32) return;
  int n = idx >> 5, i = idx & 31;
  xbf0[idx] = (i < 15) ? f2bf(x0[n * 15 + i]) : (short)0;
}

// h = relu(edge_attr @ w1 + b1)   [E,3]@[3,32]
__global__ void edge_mlp(const float* ea, const float* w1, const float* b1, float* h) {
  __shared__ float w1s[96];
  __shared__ float b1s[32];
  int t = threadIdx.x;
  if (t < 96) w1s[t] = w1[t];
  if (t < 32) b1s[t] = b1[t];
  __syncthreads();
  int e = blockIdx.x * 8 + (t >> 5);
  int k = t & 31;
  if (e < NE) {
    float a0 = ea[e * 3 + 0], a1 = ea[e * 3 + 1], a2 = ea[e * 3 + 2];
    float v = b1s[k] + a0 * w1s[k] + a1 * w1s[32 + k] + a2 * w1s[64 + k];
    h[e * 32 + k] = v > 0.f ? v : 0.f;
  }
}

// B panel: Bp[kt][n][kk] bf16 (kt = 32-wide K-step), 16B chunks XOR-swizzled
// by ((n>>1)&3).  kap = kt*32+kk = k*DIN_PAD + i;  k<32 = w2, k==32 = b2 (bias),
// k>32 zero pad; i>=DIN_DATA zero pad.
template <int DIN_DATA, int DIN_PAD, int DOUT>
__global__ void build_B(const float* w2, const float* b2, short* Bp) {
  constexpr int KTOT = NKP * DIN_PAD;
  constexpr int TOTC = (KTOT / 8) * DOUT;
  int idx = blockIdx.x * 256 + threadIdx.x;
  if (idx >= TOTC) return;
  int cc = idx & 3;
  int n = (idx >> 2) % DOUT;
  int kt = (idx >> 2) / DOUT;
  int kap0 = kt * 32 + cc * 8;
  s16x8 v;
#pragma unroll
  for (int j = 0; j < 8; ++j) {
    int kap = kap0 + j;
    int k = kap / DIN_PAD, i = kap % DIN_PAD;
    float val = 0.f;
    if (i < DIN_DATA && k <= 32)
      val = (k < 32) ? w2[(size_t)(k * DIN_DATA + i) * DOUT + n]
                     : b2[(size_t)i * DOUT + n];
    v[j] = f2bf(val);
  }
  int swz = cc ^ ((n >> 1) & 3);
  *(s16x8*)((char*)Bp + (size_t)kt * DOUT * 64 + n * 64 + swz * 16) = v;
}

// Fused gather + rank-structured GEMM; each block computes ALL k for 64 edge
// rows x (DOUT/NSPLIT) cols, plain coalesced stores into the single P slice:
//   P[e][o] = sum_k h~[e,k] * (x[src[e]] @ B_k)[o]
template <int DIN_PAD, int DOUT, int NSPLIT, int PHASE_KT>
__launch_bounds__(512, 4)
__global__ void fused_gemm(const short* xbf, const float* hedge, const short* Bp,
                           const int* srcI, float* Pout) {
  constexpr int NI = DIN_PAD / 32;        // K-steps per k
  constexpr int ROWB = DIN_PAD * 2;       // bytes per xg row
  constexpr int CHPR = ROWB / 16;         // 16B chunks per row (4/8/16)
  constexpr int CHLOG = (CHPR == 4) ? 2 : (CHPR == 8) ? 3 : 4;
  constexpr int SWZM = (CHPR >= 8) ? 7 : 3;
  constexpr int DOUT_L = DOUT / NSPLIT;   // cols per block
  constexpr int NT = DOUT_L / 64;         // 16-col frags/wave (8 waves 2Mx4N)
  constexpr int MT = 2;                   // wave covers 32 rows
  constexpr int KT_TOTAL = NKP * NI;
  constexpr int NPH = KT_TOTAL / PHASE_KT;
  constexpr int UNR = PHASE_KT * NI / cgcd(PHASE_KT, NI);
  constexpr int NSUP = KT_TOTAL / UNR;
  constexpr int PPS = UNR / PHASE_KT;
  constexpr int PHB = PHASE_KT * DOUT_L * 64;  // bytes per phase buffer
  constexpr int XGB = BMT * ROWB;
  constexpr int SMB = (XGB > 2 * PHB) ? XGB : 2 * PHB;

  __shared__ __align__(16) char smem[SMB];   // union: xg (gather) then B dbuf
  __shared__ __align__(16) short hs[NKP * BMT];
  __shared__ int src_s[BMT];

  const int t = threadIdx.x, lane = t & 63, w = t >> 6;
  const int wm = w >> 2, wn = w & 3;
  const int m0 = blockIdx.x * BMT;
  const int bn0 = blockIdx.y * DOUT_L;
  if (t < BMT) {
    int e = m0 + t;
    src_s[t] = (e < NE) ? srcI[e] : 0;
  }
  __syncthreads();

  // ---- gather xg (LDS linear dest, swizzle folded into per-lane source) ----
  constexpr int XCH = BMT * CHPR;   // 256 / 512 / 1024
#pragma unroll
  for (int rd = 0; rd < (XCH + 511) / 512; ++rd) {
    int L = rd * 512 + w * 64 + lane;
    if (XCH % 512 == 0 || L < XCH) {
      int r = L >> CHLOG, pch = L & (CHPR - 1);
      int j = pch ^ (r & SWZM);
      gload16((const char*)xbf + (size_t)src_s[r] * ROWB + j * 16,
              (char*)smem + (size_t)L * 16);
    }
  }
  // h transpose-load: hs[k][r] = h~[m0+r][k]
  for (int idx = t; idx < NKP * BMT; idx += 512) {
    int kl = idx >> 6, r = idx & 63;
    int e = m0 + r;
    float v = 0.f;
    if (e < NE) v = (kl < 32) ? hedge[e * 32 + kl] : (kl == 32 ? 1.0f : 0.f);
    hs[idx] = f2bf(v);
  }
  __syncthreads();

  // ---- hoist A fragments, then xg LDS is dead (reused for B buffers) ----
  bf16x8 afr[NI][MT];
#pragma unroll
  for (int ii = 0; ii < NI; ++ii)
#pragma unroll
    for (int mt = 0; mt < MT; ++mt) {
      int r = wm * 32 + mt * 16 + (lane & 15);
      int c = ii * 4 + (lane >> 4);
      int pos = c ^ (r & SWZM);
      afr[ii][mt] = *(const bf16x8*)((const char*)smem + r * ROWB + pos * 16);
    }
  __syncthreads();  // all waves done reading xg before B staging overwrites

  const char* Bg = (const char*)Bp + (size_t)bn0 * 64;
  auto stageB = [&](int ph, int buf) {
    char* dstB = (char*)smem + buf * PHB;
    constexpr int CPK = DOUT_L * 4;   // 16B chunks per kt slice
    constexpr int CH = PHASE_KT * CPK;
#pragma unroll
    for (int cc = 0; cc < CH / 512; ++cc) {
      int idx = cc * 512 + w * 64 + lane;
      int ktl = idx / CPK;
      int win = idx % CPK;
      gload16(Bg + (size_t)(ph * PHASE_KT + ktl) * (DOUT * 64) + (size_t)win * 16,
              dstB + (size_t)idx * 16);
    }
  };

  f32x4 msg[MT][NT], part[MT][NT];
#pragma unroll
  for (int mt = 0; mt < MT; ++mt)
#pragma unroll
    for (int nt = 0; nt < NT; ++nt)
#pragma unroll
      for (int i = 0; i < 4; ++i) { msg[mt][nt][i] = 0.f; part[mt][nt][i] = 0.f; }

  stageB(0, 0);
  __syncthreads();
  int cur = 0;
  for (int sp = 0; sp < NSUP; ++sp) {
#pragma unroll
    for (int j = 0; j < UNR; ++j) {
      if ((j % PHASE_KT) == 0) {  // prefetch next phase into other buffer
        int ph = sp * PPS + j / PHASE_KT;
        if (ph + 1 < NPH) stageB(ph + 1, cur ^ 1);
      }
      const int kt = sp * UNR + j;
      bf16x8 bfr[NT];
#pragma unroll
      for (int nt = 0; nt < NT; ++nt) {
        int n = wn * (DOUT_L / 4) + nt * 16 + (lane & 15);
        int cch = (lane >> 4) ^ ((n >> 1) & 3);
        bfr[nt] = *(const bf16x8*)((const char*)smem + cur * PHB +
                                   (j % PHASE_KT) * (DOUT_L * 64) + n * 64 + cch * 16);
      }
#pragma unroll
      for (int mt = 0; mt < MT; ++mt)
#pragma unroll
        for (int nt = 0; nt < NT; ++nt)
          part[mt][nt] = __builtin_amdgcn_mfma_f32_16x16x32_bf16(
              afr[j % NI][mt], bfr[nt], part[mt][nt], 0, 0, 0);
      if ((j % NI) == NI - 1) {  // k boundary: rescale by h[r,k]
        int kl = kt / NI;
#pragma unroll
        for (int mt = 0; mt < MT; ++mt) {
          int rb = wm * 32 + mt * 16 + (lane >> 4) * 4;
          ushort4 hv = *(const ushort4*)((const char*)hs + (size_t)(kl * BMT + rb) * 2);
          float h0 = bf2f(hv.x), h1 = bf2f(hv.y), h2 = bf2f(hv.z), h3 = bf2f(hv.w);
#pragma unroll
          for (int nt = 0; nt < NT; ++nt) {
            msg[mt][nt][0] += h0 * part[mt][nt][0];
            msg[mt][nt][1] += h1 * part[mt][nt][1];
            msg[mt][nt][2] += h2 * part[mt][nt][2];
            msg[mt][nt][3] += h3 * part[mt][nt][3];
#pragma unroll
            for (int i = 0; i < 4; ++i) part[mt][nt][i] = 0.f;
          }
        }
      }
      if ((j % PHASE_KT) == PHASE_KT - 1) {
        __syncthreads();
        cur ^= 1;
      }
    }
  }
  // ---- epilogue: plain coalesced stores ----
  float* P = Pout + (size_t)m0 * DOUT + bn0;
#pragma unroll
  for (int mt = 0; mt < MT; ++mt)
#pragma unroll
    for (int nt = 0; nt < NT; ++nt) {
      int col = wn * (DOUT_L / 4) + nt * 16 + (lane & 15);
#pragma unroll
      for (int reg = 0; reg < 4; ++reg) {
        int r = wm * 32 + mt * 16 + (lane >> 4) * 4 + reg;
        P[(size_t)r * DOUT + col] = msg[mt][nt][reg];
      }
    }
}

// per-node: mean-gather(P via CSR) + x@root + bias -> BN -> ReLU (+bf16 copy)
template <int DIN, int DOUT>
__global__ void post_node(const float* P, const float* cnt, const int* noff,
                          const int* elist, const float* xin, const float* root,
                          const float* bias, const float* bg, const float* bb,
                          const float* bm, const float* bv, float* xout, short* xbf) {
  __shared__ float xs[DIN];
  __shared__ int sh[2];
  int n = blockIdx.x;
  int o = threadIdx.x;
  if (o < DIN) xs[o] = xin[(size_t)n * DIN + o];
  if (o == 0) { sh[0] = noff[n]; sh[1] = (int)cnt[n]; }
  __syncthreads();
  int off = sh[0], c = sh[1];
  float s = 0.f;
  for (int j = 0; j < c; ++j) {
    int e = elist[off + j];
    s += P[(size_t)e * DOUT + o];
  }
  float accv = s / fmaxf((float)c, 1.f) + bias[o];
#pragma unroll 8
  for (int i = 0; i < DIN; ++i) accv += xs[i] * root[(size_t)i * DOUT + o];
  float scale = bg[o] * rsqrtf(bv[o] + 1e-5f);
  float v = (accv - bm[o]) * scale + bb[o];
  v = v > 0.f ? v : 0.f;
  xout[(size_t)n * DOUT + o] = v;
  if (xbf) xbf[(size_t)n * DOUT + o] = f2bf(v);
}

// parallel exclusive scan of per-graph counts (200 elems, one block)
__global__ void scan_offsets(const float* gcnt, const int* atom, int* goff, int* gidx) {
  __shared__ int s[256];
  int t = threadIdx.x;
  int c = (t < NG) ? (int)gcnt[t] : 0;
  s[t] = c;
  __syncthreads();
  for (int d = 1; d < 256; d <<= 1) {
    int v = (t >= d) ? s[t - d] : 0;
    __syncthreads();
    s[t] += v;
    __syncthreads();
  }
  if (t < NG) {
    int off = s[t] - c;
    goff[t] = off;
    int id = off + atom[t];
    gidx[t] = id < 0 ? 0 : (id > NN - 1 ? NN - 1 : id);  // JAX gather clamp
  }
}

__global__ void pool_kernel(const float* x3, const float* gcnt, const int* goff,
                            const int* gidx, float* hnew, float* ne_out) {
  int g = blockIdx.x, o = threadIdx.x;
  int st = goff[g];
  int cn = (int)gcnt[g];
  float s = 0.f;
  for (int n = st; n < st + cn; ++n) s += x3[(size_t)n * 256 + o];
  float ge = s / fmaxf(gcnt[g], 1.f);
  float ne = x3[(size_t)gidx[g] * 256 + o];
  ne_out[g * 256 + o] = ne;
  hnew[g * 256 + o] = 0.5f * ge + ne;
}

__global__ void final_mlp(const float* hnew, const float* mw, const float* mb, float* out) {
  __shared__ float hs[256];
  int g = blockIdx.x, j = threadIdx.x;
  hs[j] = hnew[g * 256 + j];
  __syncthreads();
  if (j < 200) {
    float accv = mb[j];
#pragma unroll 8
    for (int o = 0; o < 256; ++o) accv += hs[o] * mw[(size_t)o * 200 + j];
    out[g * 200 + j] = accv;
  }
}

// ---------------- host side ----------------

template <int DIN_DATA, int DIN_PAD, int DOUT, int NSPLIT, int PHASE_KT>
static void run_layer(void* const* d_in, int l, const float* ea, const int* srcI,
                      const short* xbf_in, const float* xin_f32, float* xout,
                      short* xbf_out, float* Pbuf, const float* cnt, const int* noff,
                      const int* elist, float* hedge, short* Bp, hipStream_t stream) {
  int base = 5 + (l - 1) * 10;
  const float* w1 = (const float*)d_in[base + 0];
  const float* b1 = (const float*)d_in[base + 1];
  const float* w2 = (const float*)d_in[base + 2];
  const float* b2 = (const float*)d_in[base + 3];
  const float* root = (const float*)d_in[base + 4];
  const float* bias = (const float*)d_in[base + 5];
  const float* bg = (const float*)d_in[base + 6];
  const float* bb = (const float*)d_in[base + 7];
  const float* bm = (const float*)d_in[base + 8];
  const float* bv = (const float*)d_in[base + 9];

  edge_mlp<<<(NE + 7) / 8, 256, 0, stream>>>(ea, w1, b1, hedge);
  constexpr int KTOT = NKP * DIN_PAD;
  build_B<DIN_DATA, DIN_PAD, DOUT>
      <<<((KTOT / 8) * DOUT + 255) / 256, 256, 0, stream>>>(w2, b2, Bp);
  fused_gemm<DIN_PAD, DOUT, NSPLIT, PHASE_KT>
      <<<dim3(MBLK, NSPLIT), 512, 0, stream>>>(xbf_in, hedge, Bp, srcI, Pbuf);
  post_node<DIN_DATA, DOUT><<<NN, DOUT, 0, stream>>>(
      Pbuf, cnt, noff, elist, xin_f32, root, bias, bg, bb, bm, bv, xout, xbf_out);
}

extern "C" void kernel_launch(void* const* d_in, const int* in_sizes, int n_in,
                              void* d_out, int out_size, void* d_ws, size_t ws_size,
                              hipStream_t stream) {
  const float* x0 = (const float*)d_in[0];
  const float* ea = (const float*)d_in[1];
  const int* eidx = (const int*)d_in[2];
  const int* batch = (const int*)d_in[3];
  const int* atom = (const int*)d_in[4];
  const float* mw = (const float*)d_in[35];
  const float* mb = (const float*)d_in[36];
  const int* srcI = eidx;
  const int* dstI = eidx + NE;
  float* out = (float*)d_out;

  char* p = (char*)d_ws;
  auto alloc = [&](size_t bytes) {
    char* r = p;
    p += (bytes + 255) & ~size_t(255);
    return r;
  };
  float* xA = (float*)alloc((size_t)NN * 256 * 4);
  float* xB = (float*)alloc((size_t)NN * 256 * 4);
  float* Pbuf = (float*)alloc((size_t)EROWS * 256 * 4);
  float* cnt = (float*)alloc(NN * 4);
  int* noff = (int*)alloc(NN * 4);
  int* fill = (int*)alloc(NN * 4);
  int* elist = (int*)alloc(NE * 4);
  float* gcnt = (float*)alloc(NG * 4);
  int* goff = (int*)alloc(NG * 4);
  int* gidx = (int*)alloc(NG * 4);
  float* hnew = (float*)alloc((size_t)NG * 256 * 4);
  float* hedge = (float*)alloc((size_t)NE * 32 * 4);
  short* Bp = (short*)alloc((size_t)NKP * 128 * 256 * 2);
  short* xbf0 = (short*)alloc((size_t)NN * 32 * 2);
  short* xbfA = (short*)alloc((size_t)NN * 64 * 2);
  short* xbfB = (short*)alloc((size_t)NN * 128 * 2);

  hipMemsetAsync(cnt, 0, NN * 4, stream);
  hipMemsetAsync(gcnt, 0, NG * 4, stream);
  count_edges<<<(NE + 255) / 256, 256, 0, stream>>>(dstI, cnt);
  count_graphs<<<(NN + 255) / 256, 256, 0, stream>>>(batch, gcnt);
  node_scan<<<1, 1024, 0, stream>>>(cnt, noff, fill);
  csr_fill<<<(NE + 255) / 256, 256, 0, stream>>>(dstI, noff, fill, elist);
  cast_x0<<<(NN * 32 + 255) / 256, 256, 0, stream>>>(x0, xbf0);

  run_layer<15, 32, 64, 1, 4>(d_in, 1, ea, srcI, xbf0, x0, xA, xbfA, Pbuf, cnt,
                              noff, elist, hedge, Bp, stream);
  run_layer<64, 64, 128, 2, 4>(d_in, 2, ea, srcI, xbfA, xA, xB, xbfB, Pbuf, cnt,
                               noff, elist, hedge, Bp, stream);
  run_layer<128, 128, 256, 2, 4>(d_in, 3, ea, srcI, xbfB, xB, xA, (short*)nullptr,
                                 Pbuf, cnt, noff, elist, hedge, Bp, stream);

  scan_offsets<<<1, 256, 0, stream>>>(gcnt, atom, goff, gidx);
  pool_kernel<<<NG, 256, 0, stream>>>(xA, gcnt, goff, gidx, hnew, out + 40000);
  final_mlp<<<NG, 256, 0, stream>>>(hnew, mw, mb, out);
}

// Round 5
// 327.764 us; speedup vs baseline: 1.4062x; 1.2892x over previous
//
#include <hip/hip_runtime.h>
#include <stdint.h>

#define DEVINL __device__ __forceinline__

typedef __attribute__((ext_vector_type(8))) __bf16 bf16x8;
typedef __attribute__((ext_vector_type(8))) short s16x8;
typedef __attribute__((ext_vector_type(4))) float f32x4;

constexpr int NN = 5000;   // nodes
constexpr int NE = 10000;  // edges
constexpr int NG = 200;    // graphs
constexpr int BM = 128;                    // edge rows per block
constexpr int MBLK = (NE + BM - 1) / BM;   // 79
constexpr int EROWS = MBLK * BM;           // 10112
constexpr int NKP = 36;                    // padded k count (33 real: 32 + bias)
constexpr int PHKT = 6;                    // kt per pipeline phase

constexpr int cgcd(int a, int b) { return b == 0 ? a : cgcd(b, a % b); }

DEVINL short f2bf(float f) {  // RNE fp32->bf16
  union { float f; unsigned u; } v; v.f = f;
  unsigned u = v.u + 0x7fffu + ((v.u >> 16) & 1u);
  return (short)(u >> 16);
}

DEVINL void gload16(const void* g, void* l) {
  __builtin_amdgcn_global_load_lds(
      (const __attribute__((address_space(1))) void*)g,
      (__attribute__((address_space(3))) void*)l, 16, 0, 0);
}

// ---------------- small kernels ----------------

// merged: edge-degree count, graph count, x0 pad-cast
__global__ void prep(const int* dst, const int* batch, const float* x0,
                     float* cnt, float* gcnt, short* xbf0) {
  int idx = blockIdx.x * 256 + threadIdx.x;
  if (idx < NE) atomicAdd(&cnt[dst[idx]], 1.0f);
  if (idx < NN) atomicAdd(&gcnt[batch[idx]], 1.0f);
  if (idx < NN * 32) {
    int n = idx >> 5, i = idx & 31;
    xbf0[idx] = (i < 15) ? f2bf(x0[n * 15 + i]) : (short)0;
  }
}

// exclusive scan of node edge-counts -> noff; zeroes fill
__global__ void node_scan(const float* cnt, int* noff, int* fill) {
  __shared__ int s[1024];
  __shared__ int carry;
  int t = threadIdx.x;
  if (t == 0) carry = 0;
  __syncthreads();
  for (int c0 = 0; c0 < NN; c0 += 1024) {
    int i = c0 + t;
    int v = (i < NN) ? (int)cnt[i] : 0;
    s[t] = v;
    __syncthreads();
    for (int d = 1; d < 1024; d <<= 1) {
      int u = (t >= d) ? s[t - d] : 0;
      __syncthreads();
      s[t] += u;
      __syncthreads();
    }
    if (i < NN) { noff[i] = carry + s[t] - v; fill[i] = 0; }
    __syncthreads();
    if (t == 0) carry += s[1023];
    __syncthreads();
  }
}

__global__ void csr_fill(const int* dst, const int* noff, int* fill, int* elist) {
  int e = blockIdx.x * 256 + threadIdx.x;
  if (e < NE) {
    int n = dst[e];
    int p = noff[n] + atomicAdd(&fill[n], 1);
    elist[p] = e;
  }
}

// hedgeT[k][e] bf16 for k in [0,36): k<32 = relu(ea@w1+b1), k==32 = 1, else 0.
// grid: (ceil(EROWS/256), 36); coalesced writes.
__global__ void edge_mlp_T(const float* ea, const float* w1, const float* b1,
                           short* ht) {
  __shared__ float w1s[3];
  __shared__ float b1s;
  int t = threadIdx.x;
  int k = blockIdx.y;
  if (t < 3 && k < 32) w1s[t] = w1[t * 32 + k];
  if (t == 0 && k < 32) b1s = b1[k];
  __syncthreads();
  int e = blockIdx.x * 256 + t;
  if (e >= EROWS) return;
  float v = 0.f;
  if (e < NE) {
    if (k < 32) {
      float a = b1s + ea[e * 3] * w1s[0] + ea[e * 3 + 1] * w1s[1] +
                ea[e * 3 + 2] * w1s[2];
      v = a > 0.f ? a : 0.f;
    } else if (k == 32) {
      v = 1.0f;
    }
  }
  ht[(size_t)k * EROWS + e] = f2bf(v);
}

// B panel: Bp[kt][n][kk] bf16 (kt = 32-wide K-step), 16B chunks XOR-swizzled
// by ((n>>1)&3).  kap = kt*32+kk = k*DIN_PAD + i;  k<32 = w2, k==32 = b2,
// k>32 zero pad; i>=DIN_DATA zero pad.
template <int DIN_DATA, int DIN_PAD, int DOUT>
__global__ void build_B(const float* w2, const float* b2, short* Bp) {
  constexpr int KTOT = NKP * DIN_PAD;
  constexpr int TOTC = (KTOT / 8) * DOUT;
  int idx = blockIdx.x * 256 + threadIdx.x;
  if (idx >= TOTC) return;
  int cc = idx & 3;
  int n = (idx >> 2) % DOUT;
  int kt = (idx >> 2) / DOUT;
  int kap0 = kt * 32 + cc * 8;
  s16x8 v;
#pragma unroll
  for (int j = 0; j < 8; ++j) {
    int kap = kap0 + j;
    int k = kap / DIN_PAD, i = kap % DIN_PAD;
    float val = 0.f;
    if (i < DIN_DATA && k <= 32)
      val = (k < 32) ? w2[(size_t)(k * DIN_DATA + i) * DOUT + n]
                     : b2[(size_t)i * DOUT + n];
    v[j] = f2bf(val);
  }
  int swz = cc ^ ((n >> 1) & 3);
  *(s16x8*)((char*)Bp + (size_t)kt * DOUT * 64 + n * 64 + swz * 16) = v;
}

// Fused gather + rank-structured GEMM, plain stores into P column slice:
//   P[e][bn0+o] = sum_k ht[k][e] * (xbf[src[e]] @ B_k)[bn0+o]
template <int DIN_PAD, int DOUT, int NSPLIT>
__launch_bounds__(512)
__global__ void fused_gemm(const short* xbf, const short* ht, const short* Bp,
                           const int* srcI, float* Pout) {
  constexpr int NI = DIN_PAD / 32;        // K-steps per k
  constexpr int ROWB = DIN_PAD * 2;       // bytes per xg row
  constexpr int CHPR = ROWB / 16;         // 16B chunks per row (4/8/16)
  constexpr int CHLOG = (CHPR == 4) ? 2 : (CHPR == 8) ? 3 : 4;
  constexpr int SWZM = (CHPR >= 8) ? 7 : 3;
  constexpr int DOUT_L = DOUT / NSPLIT;   // 64 cols per block
  constexpr int NT = DOUT_L / 64;         // = 1
  constexpr int MT = 4;                   // wave covers 64 rows (2M x 4N waves)
  constexpr int KT_TOTAL = NKP * NI;
  constexpr int NPH = KT_TOTAL / PHKT;
  constexpr int UNR = PHKT * NI / cgcd(PHKT, NI);
  constexpr int NSUP = KT_TOTAL / UNR;
  constexpr int PPS = UNR / PHKT;
  constexpr int PHB = PHKT * DOUT_L * 64;   // 24 KB per phase buffer
  constexpr int XGB = BM * ROWB;
  constexpr int SMB = (XGB > 2 * PHB) ? XGB : 2 * PHB;

  __shared__ __align__(16) char smem[SMB];     // union: xg, then B dbuf
  __shared__ __align__(16) short hs[NKP * BM]; // hs[k][r] bf16
  __shared__ int src_s[BM];

  const int t = threadIdx.x, lane = t & 63, w = t >> 6;
  const int wm = w >> 2, wn = w & 3;
  const int m0 = blockIdx.x * BM;
  const int bn0 = blockIdx.y * DOUT_L;
  if (t < BM) {
    int e = m0 + t;
    src_s[t] = (e < NE) ? srcI[e] : 0;
  }
  __syncthreads();

  // ---- gather xg (LDS linear dest, swizzle folded into per-lane source) ----
  constexpr int XCH = BM * CHPR;  // 512/1024/2048
#pragma unroll
  for (int rd = 0; rd < XCH / 512; ++rd) {
    int L = rd * 512 + w * 64 + lane;
    int r = L >> CHLOG, pch = L & (CHPR - 1);
    int j = pch ^ (r & SWZM);
    gload16((const char*)xbf + (size_t)src_s[r] * ROWB + j * 16,
            (char*)smem + (size_t)L * 16);
  }
  // ---- stage hs[k][0..BM) = ht[k][m0..m0+BM) : 36*16 = 576 16B chunks ----
  for (int idx = t; idx < NKP * (BM / 8); idx += 512) {
    int kl = idx >> 4, c = idx & 15;
    gload16((const char*)ht + ((size_t)kl * EROWS + m0 + c * 8) * 2,
            (char*)hs + (size_t)idx * 16);
  }
  __syncthreads();

  // ---- hoist A fragments; afterwards xg LDS is dead (reused for B dbuf) ----
  bf16x8 afr[NI][MT];
#pragma unroll
  for (int ii = 0; ii < NI; ++ii)
#pragma unroll
    for (int mt = 0; mt < MT; ++mt) {
      int r = wm * 64 + mt * 16 + (lane & 15);
      int c = ii * 4 + (lane >> 4);
      int pos = c ^ (r & SWZM);
      afr[ii][mt] = *(const bf16x8*)((const char*)smem + r * ROWB + pos * 16);
    }
  __syncthreads();

  const char* Bg = (const char*)Bp + (size_t)bn0 * 64;
  auto stageB = [&](int ph, int buf) {
    char* dstB = (char*)smem + buf * PHB;
    constexpr int CPK = DOUT_L * 4;       // 256 chunks per kt slice
    constexpr int CH = PHKT * CPK;        // 1536 chunks
#pragma unroll
    for (int cc = 0; cc < CH / 512; ++cc) {
      int idx = cc * 512 + w * 64 + lane;
      int ktl = idx / CPK;
      int win = idx % CPK;
      gload16(Bg + (size_t)(ph * PHKT + ktl) * (DOUT * 64) + (size_t)win * 16,
              dstB + (size_t)idx * 16);
    }
  };

  f32x4 msg[MT][NT], part[MT][NT];
#pragma unroll
  for (int mt = 0; mt < MT; ++mt)
#pragma unroll
    for (int nt = 0; nt < NT; ++nt)
#pragma unroll
      for (int i = 0; i < 4; ++i) { msg[mt][nt][i] = 0.f; part[mt][nt][i] = 0.f; }

  stageB(0, 0);
  __syncthreads();
  int cur = 0;
  for (int sp = 0; sp < NSUP; ++sp) {
#pragma unroll
    for (int j = 0; j < UNR; ++j) {
      if ((j % PHKT) == 0) {  // prefetch next phase into other buffer
        int ph = sp * PPS + j / PHKT;
        if (ph + 1 < NPH) stageB(ph + 1, cur ^ 1);
      }
      const int kt = sp * UNR + j;
      bf16x8 bfr[NT];
#pragma unroll
      for (int nt = 0; nt < NT; ++nt) {
        int n = wn * (DOUT_L / 4) + nt * 16 + (lane & 15);
        int cch = (lane >> 4) ^ ((n >> 1) & 3);
        bfr[nt] = *(const bf16x8*)((const char*)smem + cur * PHB +
                                   (j % PHKT) * (DOUT_L * 64) + n * 64 + cch * 16);
      }
#pragma unroll
      for (int mt = 0; mt < MT; ++mt)
#pragma unroll
        for (int nt = 0; nt < NT; ++nt)
          part[mt][nt] = __builtin_amdgcn_mfma_f32_16x16x32_bf16(
              afr[j % NI][mt], bfr[nt], part[mt][nt], 0, 0, 0);
      if ((j % NI) == NI - 1) {  // k boundary: rescale by h[r,k]
        int kl = kt / NI;
#pragma unroll
        for (int mt = 0; mt < MT; ++mt) {
          int rb = wm * 64 + mt * 16 + (lane >> 4) * 4;
          ushort4 hv = *(const ushort4*)((const char*)hs + (size_t)(kl * BM + rb) * 2);
          float h0, h1, h2, h3;
          { union { unsigned u; float f; } c;
            c.u = (unsigned)hv.x << 16; h0 = c.f;
            c.u = (unsigned)hv.y << 16; h1 = c.f;
            c.u = (unsigned)hv.z << 16; h2 = c.f;
            c.u = (unsigned)hv.w << 16; h3 = c.f; }
#pragma unroll
          for (int nt = 0; nt < NT; ++nt) {
            msg[mt][nt][0] += h0 * part[mt][nt][0];
            msg[mt][nt][1] += h1 * part[mt][nt][1];
            msg[mt][nt][2] += h2 * part[mt][nt][2];
            msg[mt][nt][3] += h3 * part[mt][nt][3];
#pragma unroll
            for (int i = 0; i < 4; ++i) part[mt][nt][i] = 0.f;
          }
        }
      }
      if ((j % PHKT) == PHKT - 1) {
        __syncthreads();
        cur ^= 1;
      }
    }
  }
  // ---- epilogue: plain stores ----
  float* P = Pout + (size_t)m0 * DOUT + bn0;
#pragma unroll
  for (int mt = 0; mt < MT; ++mt)
#pragma unroll
    for (int nt = 0; nt < NT; ++nt) {
      int col = wn * (DOUT_L / 4) + nt * 16 + (lane & 15);
#pragma unroll
      for (int reg = 0; reg < 4; ++reg) {
        int r = wm * 64 + mt * 16 + (lane >> 4) * 4 + reg;
        P[(size_t)r * DOUT + col] = msg[mt][nt][reg];
      }
    }
}

// per-node (8/block): mean-gather(P via CSR) + x@root + bias -> BN -> ReLU
template <int DIN, int DOUT>
__launch_bounds__(256)
__global__ void post_node(const float* P, const float* cnt, const int* noff,
                          const int* elist, const float* xin, const float* root,
                          const float* bias, const float* bg, const float* bb,
                          const float* bm, const float* bv, float* xout, short* xbf) {
  constexpr int NPB = 8;
  __shared__ float xs[NPB * DIN];
  __shared__ int offs[NPB], cnts[NPB];
  int n0 = blockIdx.x * NPB;
  int o = threadIdx.x;
  if (o < NPB) {
    int n = n0 + o;
    offs[o] = (n < NN) ? noff[n] : 0;
    cnts[o] = (n < NN) ? (int)cnt[n] : 0;
  }
  for (int idx = o; idx < NPB * DIN; idx += DOUT) {
    int n = n0 + idx / DIN;
    xs[idx] = (n < NN) ? xin[(size_t)n * DIN + idx % DIN] : 0.f;
  }
  __syncthreads();
  float acc[NPB];
#pragma unroll
  for (int nn = 0; nn < NPB; ++nn) acc[nn] = 0.f;
  for (int i = 0; i < DIN; ++i) {
    float rv = root[(size_t)i * DOUT + o];
#pragma unroll
    for (int nn = 0; nn < NPB; ++nn) acc[nn] += xs[nn * DIN + i] * rv;
  }
  float bi = bias[o];
  float scale = bg[o] * rsqrtf(bv[o] + 1e-5f);
  float mo = bm[o], bo = bb[o];
#pragma unroll
  for (int nn = 0; nn < NPB; ++nn) {
    int n = n0 + nn;
    if (n >= NN) break;
    int off = offs[nn], c = cnts[nn];
    float s = 0.f;
    for (int j = 0; j < c; ++j) {
      int e = elist[off + j];
      s += P[(size_t)e * DOUT + o];
    }
    float accv = s / fmaxf((float)c, 1.f) + bi + acc[nn];
    float v = (accv - mo) * scale + bo;
    v = v > 0.f ? v : 0.f;
    xout[(size_t)n * DOUT + o] = v;
    if (xbf) xbf[(size_t)n * DOUT + o] = f2bf(v);
  }
}

// parallel exclusive scan of per-graph counts (200 elems, one block)
__global__ void scan_offsets(const float* gcnt, const int* atom, int* goff, int* gidx) {
  __shared__ int s[256];
  int t = threadIdx.x;
  int c = (t < NG) ? (int)gcnt[t] : 0;
  s[t] = c;
  __syncthreads();
  for (int d = 1; d < 256; d <<= 1) {
    int v = (t >= d) ? s[t - d] : 0;
    __syncthreads();
    s[t] += v;
    __syncthreads();
  }
  if (t < NG) {
    int off = s[t] - c;
    goff[t] = off;
    int id = off + atom[t];
    gidx[t] = id < 0 ? 0 : (id > NN - 1 ? NN - 1 : id);  // JAX gather clamp
  }
}

__global__ void pool_kernel(const float* x3, const float* gcnt, const int* goff,
                            const int* gidx, float* hnew, float* ne_out) {
  int g = blockIdx.x, o = threadIdx.x;
  int st = goff[g];
  int cn = (int)gcnt[g];
  float s = 0.f;
  for (int n = st; n < st + cn; ++n) s += x3[(size_t)n * 256 + o];
  float ge = s / fmaxf(gcnt[g], 1.f);
  float ne = x3[(size_t)gidx[g] * 256 + o];
  ne_out[g * 256 + o] = ne;
  hnew[g * 256 + o] = 0.5f * ge + ne;
}

__global__ void final_mlp(const float* hnew, const float* mw, const float* mb, float* out) {
  __shared__ float hs[256];
  int g = blockIdx.x, j = threadIdx.x;
  hs[j] = hnew[g * 256 + j];
  __syncthreads();
  if (j < 200) {
    float accv = mb[j];
#pragma unroll 8
    for (int o = 0; o < 256; ++o) accv += hs[o] * mw[(size_t)o * 200 + j];
    out[g * 200 + j] = accv;
  }
}

// ---------------- host side ----------------

template <int DIN_DATA, int DIN_PAD, int DOUT, int NSPLIT>
static void run_layer(void* const* d_in, int l, const float* ea, const int* srcI,
                      const short* xbf_in, const float* xin_f32, float* xout,
                      short* xbf_out, float* Pbuf, const float* cnt, const int* noff,
                      const int* elist, short* ht, short* Bp, hipStream_t stream) {
  int base = 5 + (l - 1) * 10;
  const float* w1 = (const float*)d_in[base + 0];
  const float* b1 = (const float*)d_in[base + 1];
  const float* w2 = (const float*)d_in[base + 2];
  const float* b2 = (const float*)d_in[base + 3];
  const float* root = (const float*)d_in[base + 4];
  const float* bias = (const float*)d_in[base + 5];
  const float* bg = (const float*)d_in[base + 6];
  const float* bb = (const float*)d_in[base + 7];
  const float* bm = (const float*)d_in[base + 8];
  const float* bv = (const float*)d_in[base + 9];

  edge_mlp_T<<<dim3((EROWS + 255) / 256, NKP), 256, 0, stream>>>(ea, w1, b1, ht);
  constexpr int KTOT = NKP * DIN_PAD;
  build_B<DIN_DATA, DIN_PAD, DOUT>
      <<<((KTOT / 8) * DOUT + 255) / 256, 256, 0, stream>>>(w2, b2, Bp);
  fused_gemm<DIN_PAD, DOUT, NSPLIT>
      <<<dim3(MBLK, NSPLIT), 512, 0, stream>>>(xbf_in, ht, Bp, srcI, Pbuf);
  post_node<DIN_DATA, DOUT><<<(NN + 7) / 8, DOUT, 0, stream>>>(
      Pbuf, cnt, noff, elist, xin_f32, root, bias, bg, bb, bm, bv, xout, xbf_out);
}

extern "C" void kernel_launch(void* const* d_in, const int* in_sizes, int n_in,
                              void* d_out, int out_size, void* d_ws, size_t ws_size,
                              hipStream_t stream) {
  const float* x0 = (const float*)d_in[0];
  const float* ea = (const float*)d_in[1];
  const int* eidx = (const int*)d_in[2];
  const int* batch = (const int*)d_in[3];
  const int* atom = (const int*)d_in[4];
  const float* mw = (const float*)d_in[35];
  const float* mb = (const float*)d_in[36];
  const int* srcI = eidx;
  const int* dstI = eidx + NE;
  float* out = (float*)d_out;

  char* p = (char*)d_ws;
  auto alloc = [&](size_t bytes) {
    char* r = p;
    p += (bytes + 255) & ~size_t(255);
    return r;
  };
  float* xA = (float*)alloc((size_t)NN * 256 * 4);
  float* xB = (float*)alloc((size_t)NN * 256 * 4);
  float* Pbuf = (float*)alloc((size_t)EROWS * 256 * 4);
  float* cnt = (float*)alloc(NN * 4);
  int* noff = (int*)alloc(NN * 4);
  int* fill = (int*)alloc(NN * 4);
  int* elist = (int*)alloc(NE * 4);
  float* gcnt = (float*)alloc(NG * 4);
  int* goff = (int*)alloc(NG * 4);
  int* gidx = (int*)alloc(NG * 4);
  float* hnew = (float*)alloc((size_t)NG * 256 * 4);
  short* ht = (short*)alloc((size_t)NKP * EROWS * 2);
  short* Bp = (short*)alloc((size_t)NKP * 128 * 256 * 2);
  short* xbf0 = (short*)alloc((size_t)NN * 32 * 2);
  short* xbfA = (short*)alloc((size_t)NN * 64 * 2);
  short* xbfB = (short*)alloc((size_t)NN * 128 * 2);

  hipMemsetAsync(cnt, 0, NN * 4, stream);
  hipMemsetAsync(gcnt, 0, NG * 4, stream);
  prep<<<(NN * 32 + 255) / 256, 256, 0, stream>>>(dstI, batch, x0, cnt, gcnt, xbf0);
  node_scan<<<1, 1024, 0, stream>>>(cnt, noff, fill);
  csr_fill<<<(NE + 255) / 256, 256, 0, stream>>>(dstI, noff, fill, elist);

  run_layer<15, 32, 64, 1>(d_in, 1, ea, srcI, xbf0, x0, xA, xbfA, Pbuf, cnt,
                           noff, elist, ht, Bp, stream);
  run_layer<64, 64, 128, 2>(d_in, 2, ea, srcI, xbfA, xA, xB, xbfB, Pbuf, cnt,
                            noff, elist, ht, Bp, stream);
  run_layer<128, 128, 256, 4>(d_in, 3, ea, srcI, xbfB, xB, xA, (short*)nullptr,
                              Pbuf, cnt, noff, elist, ht, Bp, stream);

  scan_offsets<<<1, 256, 0, stream>>>(gcnt, atom, goff, gidx);
  pool_kernel<<<NG, 256, 0, stream>>>(xA, gcnt, goff, gidx, hnew, out + 40000);
  final_mlp<<<NG, 256, 0, stream>>>(hnew, mw, mb, out);
}

// Round 6
// 303.360 us; speedup vs baseline: 1.5193x; 1.0804x over previous
//
#include <hip/hip_runtime.h>
#include <stdint.h>

#define DEVINL __device__ __forceinline__

typedef __attribute__((ext_vector_type(8))) __bf16 bf16x8;
typedef __attribute__((ext_vector_type(8))) short s16x8;
typedef __attribute__((ext_vector_type(4))) float f32x4;

constexpr int NN = 5000;   // nodes
constexpr int NE = 10000;  // edges
constexpr int NG = 200;    // graphs
constexpr int BM = 64;                     // edge rows per block
constexpr int MBLK = (NE + BM - 1) / BM;   // 158
constexpr int EROWS = MBLK * BM;           // 10112
constexpr int NKP = 36;                    // built k rows (33 real: 32 + bias)
constexpr int PHKT = 4;                    // kt per pipeline phase

DEVINL short f2bf(float f) {  // RNE fp32->bf16
  union { float f; unsigned u; } v; v.f = f;
  unsigned u = v.u + 0x7fffu + ((v.u >> 16) & 1u);
  return (short)(u >> 16);
}

DEVINL void gload16(const void* g, void* l) {
  __builtin_amdgcn_global_load_lds(
      (const __attribute__((address_space(1))) void*)g,
      (__attribute__((address_space(3))) void*)l, 16, 0, 0);
}

// ---------------- prep / CSR ----------------

__global__ void prep(const int* dst, const int* batch, const float* x0,
                     float* cnt, float* gcnt, short* xbf0) {
  int idx = blockIdx.x * 256 + threadIdx.x;
  if (idx < NE) atomicAdd(&cnt[dst[idx]], 1.0f);
  if (idx < NN) atomicAdd(&gcnt[batch[idx]], 1.0f);
  if (idx < NN * 32) {
    int n = idx >> 5, i = idx & 31;
    xbf0[idx] = (i < 15) ? f2bf(x0[n * 15 + i]) : (short)0;
  }
}

__global__ void node_scan(const float* cnt, int* noff, int* fill) {
  __shared__ int s[1024];
  __shared__ int carry;
  int t = threadIdx.x;
  if (t == 0) carry = 0;
  __syncthreads();
  for (int c0 = 0; c0 < NN; c0 += 1024) {
    int i = c0 + t;
    int v = (i < NN) ? (int)cnt[i] : 0;
    s[t] = v;
    __syncthreads();
    for (int d = 1; d < 1024; d <<= 1) {
      int u = (t >= d) ? s[t - d] : 0;
      __syncthreads();
      s[t] += u;
      __syncthreads();
    }
    if (i < NN) { noff[i] = carry + s[t] - v; fill[i] = 0; }
    __syncthreads();
    if (t == 0) carry += s[1023];
    __syncthreads();
  }
}

__global__ void csr_fill(const int* dst, const int* noff, int* fill, int* elist) {
  int e = blockIdx.x * 256 + threadIdx.x;
  if (e < NE) {
    int n = dst[e];
    int p = noff[n] + atomicAdd(&fill[n], 1);
    elist[p] = e;
  }
}

// ---------------- edge MLP (all 3 layers, transposed bf16 out) ----------------

__global__ void edge_mlp_all(const float* ea,
                             const float* w1a, const float* b1a,
                             const float* w1b, const float* b1b,
                             const float* w1c, const float* b1c,
                             short* hta, short* htb, short* htc) {
  int L = blockIdx.z;
  const float* w1 = (L == 0) ? w1a : (L == 1) ? w1b : w1c;
  const float* b1 = (L == 0) ? b1a : (L == 1) ? b1b : b1c;
  short* ht = (L == 0) ? hta : (L == 1) ? htb : htc;
  __shared__ float w1s[3];
  __shared__ float b1s;
  int t = threadIdx.x;
  int k = blockIdx.y;
  if (t < 3 && k < 32) w1s[t] = w1[t * 32 + k];
  if (t == 0 && k < 32) b1s = b1[k];
  __syncthreads();
  int e = blockIdx.x * 256 + t;
  if (e >= EROWS) return;
  float v = 0.f;
  if (e < NE) {
    if (k < 32) {
      float a = b1s + ea[e * 3] * w1s[0] + ea[e * 3 + 1] * w1s[1] +
                ea[e * 3 + 2] * w1s[2];
      v = a > 0.f ? a : 0.f;
    } else if (k == 32) {
      v = 1.0f;
    }
  }
  ht[(size_t)k * EROWS + e] = f2bf(v);
}

// ---------------- B panels (all 3 layers) ----------------
// Bp[kt][n][kk] bf16, 16B chunks XOR-swizzled by ((n>>1)&3).
// kap = kt*32+kk = k*DIN_PAD+i; k<32 = w2, k==32 = b2, k>32 pad; i>=DIN_DATA pad.

template <int DIN_DATA, int DIN_PAD, int DOUT>
DEVINL void buildB_one(int idx, const float* w2, const float* b2, short* Bp) {
  int cc = idx & 3;
  int n = (idx >> 2) % DOUT;
  int kt = (idx >> 2) / DOUT;
  int kap0 = kt * 32 + cc * 8;
  s16x8 v;
#pragma unroll
  for (int j = 0; j < 8; ++j) {
    int kap = kap0 + j;
    int k = kap / DIN_PAD, i = kap % DIN_PAD;
    float val = 0.f;
    if (i < DIN_DATA && k <= 32)
      val = (k < 32) ? w2[(size_t)(k * DIN_DATA + i) * DOUT + n]
                     : b2[(size_t)i * DOUT + n];
    v[j] = f2bf(val);
  }
  int swz = cc ^ ((n >> 1) & 3);
  *(s16x8*)((char*)Bp + (size_t)kt * DOUT * 64 + n * 64 + swz * 16) = v;
}

constexpr int BCH1 = (NKP * 32 / 8) * 64;    // 9216
constexpr int BCH2 = (NKP * 64 / 8) * 128;   // 36864
constexpr int BCH3 = (NKP * 128 / 8) * 256;  // 147456

__global__ void build_B_all(const float* w2a, const float* b2a,
                            const float* w2b, const float* b2b,
                            const float* w2c, const float* b2c,
                            short* Bp1, short* Bp2, short* Bp3) {
  int idx = blockIdx.x * 256 + threadIdx.x;
  if (idx < BCH1) {
    buildB_one<15, 32, 64>(idx, w2a, b2a, Bp1);
  } else if (idx < BCH1 + BCH2) {
    buildB_one<64, 64, 128>(idx - BCH1, w2b, b2b, Bp2);
  } else if (idx < BCH1 + BCH2 + BCH3) {
    buildB_one<128, 128, 256>(idx - BCH1 - BCH2, w2c, b2c, Bp3);
  }
}

// ---------------- fused gather + rank-structured GEMM ----------------
//   P[e][bn0+o] = sum_k ht[k][e] * (xbf[src[e]] @ B_k)[bn0+o]
// Counted-vmcnt phase pipeline: prefetch crosses barriers (never drain to 0
// in the loop).  2 gload16/thread/phase -> steady wait = vmcnt(2).

template <int DIN_PAD, int DOUT, int NSPLIT, int NKPE>
__launch_bounds__(512)
__global__ void fused_gemm(const short* xbf, const short* ht, const short* Bp,
                           const int* srcI, float* Pout) {
  constexpr int NI = DIN_PAD / 32;        // K-steps per k
  constexpr int ROWB = DIN_PAD * 2;       // bytes per xg row
  constexpr int CHPR = ROWB / 16;         // 16B chunks per row (4/8/16)
  constexpr int CHLOG = (CHPR == 4) ? 2 : (CHPR == 8) ? 3 : 4;
  constexpr int SWZM = (CHPR >= 8) ? 7 : 3;
  constexpr int DOUT_L = DOUT / NSPLIT;   // 64 cols per block
  constexpr int MT = 2;                   // wave covers 32 rows (2M x 4N waves)
  constexpr int KT_TOTAL = NKPE * NI;
  constexpr int NPH = KT_TOTAL / PHKT;
  static_assert(KT_TOTAL % PHKT == 0, "phase align");
  static_assert(PHKT % NI == 0 || NI % PHKT == 0, "k align");
  constexpr int PHB = PHKT * DOUT_L * 64; // 16 KB per phase buffer
  constexpr int CPK = DOUT_L * 4;         // 16B chunks per kt slice (256)
  constexpr int CH = PHKT * CPK;          // 1024 chunks per stage = 2/thread
  constexpr int XGB = BM * ROWB;
  constexpr int SMB = (XGB > 2 * PHB) ? XGB : 2 * PHB;

  __shared__ __align__(16) char smem[SMB];       // union: xg, then B dbuf
  __shared__ __align__(16) short hs[NKPE * BM];  // hs[k][r]
  __shared__ int src_s[BM];

  const int t = threadIdx.x, lane = t & 63, w = t >> 6;
  const int wm = w >> 2, wn = w & 3;
  const int m0 = blockIdx.x * BM;
  const int bn0 = blockIdx.y * DOUT_L;
  if (t < BM) {
    int e = m0 + t;
    src_s[t] = (e < NE) ? srcI[e] : 0;
  }
  __syncthreads();

  // ---- gather xg (LDS linear dest, swizzle folded into per-lane source) ----
  constexpr int XCH = BM * CHPR;  // 256/512/1024
#pragma unroll
  for (int rd = 0; rd < (XCH + 511) / 512; ++rd) {
    int L = rd * 512 + t;
    if (XCH % 512 == 0 || L < XCH) {
      int r = L >> CHLOG, pch = L & (CHPR - 1);
      int j = pch ^ (r & SWZM);
      gload16((const char*)xbf + (size_t)src_s[r] * ROWB + j * 16,
              (char*)smem + (size_t)L * 16);
    }
  }
  // ---- stage hs[k][0..BM) = ht[k][m0..m0+BM) : NKPE*8 chunks ----
  {
    int idx = t;
    if (idx < NKPE * (BM / 8)) {
      int kl = idx >> 3, c = idx & 7;
      gload16((const char*)ht + ((size_t)kl * EROWS + m0) * 2 + c * 16,
              (char*)hs + (size_t)idx * 16);
    }
  }
  __syncthreads();  // full drain: xg + hs resident

  // ---- hoist A fragments; afterwards xg LDS is dead (reused for B dbuf) ----
  bf16x8 afr[NI][MT];
#pragma unroll
  for (int ii = 0; ii < NI; ++ii)
#pragma unroll
    for (int mt = 0; mt < MT; ++mt) {
      int r = wm * 32 + mt * 16 + (lane & 15);
      int c = ii * 4 + (lane >> 4);
      int pos = c ^ (r & SWZM);
      afr[ii][mt] = *(const bf16x8*)((const char*)smem + r * ROWB + pos * 16);
    }
  asm volatile("s_waitcnt lgkmcnt(0)" ::: "memory");
  __builtin_amdgcn_sched_barrier(0);
  __builtin_amdgcn_s_barrier();  // all waves: afr read done before overwrite

  const char* Bg = (const char*)Bp + (size_t)bn0 * 64;
  auto stageB = [&](int ph, int buf) {
    char* dstB = (char*)smem + buf * PHB;
#pragma unroll
    for (int cc = 0; cc < CH / 512; ++cc) {
      int idx = cc * 512 + t;
      int ktl = idx / CPK;
      int win = idx % CPK;
      gload16(Bg + (size_t)(ph * PHKT + ktl) * (DOUT * 64) + (size_t)win * 16,
              dstB + (size_t)idx * 16);
    }
  };

  f32x4 msg[MT], part[MT];
#pragma unroll
  for (int mt = 0; mt < MT; ++mt)
#pragma unroll
    for (int i = 0; i < 4; ++i) { msg[mt][i] = 0.f; part[mt][i] = 0.f; }

  stageB(0, 0);  // 2 loads in flight
  int cur = 0;
  for (int ph = 0; ph < NPH; ++ph) {
    if (ph + 1 < NPH) {
      stageB(ph + 1, cur ^ 1);                       // +2 loads
      asm volatile("s_waitcnt vmcnt(2)" ::: "memory");  // wait older 2
    } else {
      asm volatile("s_waitcnt vmcnt(0)" ::: "memory");
    }
    __builtin_amdgcn_s_barrier();
    __builtin_amdgcn_sched_barrier(0);
#pragma unroll
    for (int j = 0; j < PHKT; ++j) {
      const int kt = ph * PHKT + j;
      bf16x8 bfr;
      {
        int n = wn * 16 + (lane & 15);
        int cch = (lane >> 4) ^ ((n >> 1) & 3);
        bfr = *(const bf16x8*)((const char*)smem + cur * PHB +
                               j * (DOUT_L * 64) + n * 64 + cch * 16);
      }
#pragma unroll
      for (int mt = 0; mt < MT; ++mt)
        part[mt] = __builtin_amdgcn_mfma_f32_16x16x32_bf16(
            afr[j % NI][mt], bfr, part[mt], 0, 0, 0);
      if ((j % NI) == NI - 1) {  // k boundary: rescale by h[r,k]
        int kl = kt / NI;
#pragma unroll
        for (int mt = 0; mt < MT; ++mt) {
          int rb = wm * 32 + mt * 16 + (lane >> 4) * 4;
          ushort4 hv = *(const ushort4*)((const char*)hs + (size_t)(kl * BM + rb) * 2);
          float h0, h1, h2, h3;
          { union { unsigned u; float f; } c;
            c.u = (unsigned)hv.x << 16; h0 = c.f;
            c.u = (unsigned)hv.y << 16; h1 = c.f;
            c.u = (unsigned)hv.z << 16; h2 = c.f;
            c.u = (unsigned)hv.w << 16; h3 = c.f; }
          msg[mt][0] += h0 * part[mt][0];
          msg[mt][1] += h1 * part[mt][1];
          msg[mt][2] += h2 * part[mt][2];
          msg[mt][3] += h3 * part[mt][3];
#pragma unroll
          for (int i = 0; i < 4; ++i) part[mt][i] = 0.f;
        }
      }
    }
    __builtin_amdgcn_sched_barrier(0);
    __builtin_amdgcn_s_barrier();  // reads done before next overwrite
    cur ^= 1;
  }
  // ---- epilogue: plain stores ----
  float* P = Pout + (size_t)m0 * DOUT + bn0;
#pragma unroll
  for (int mt = 0; mt < MT; ++mt) {
    int col = wn * 16 + (lane & 15);
#pragma unroll
    for (int reg = 0; reg < 4; ++reg) {
      int r = wm * 32 + mt * 16 + (lane >> 4) * 4 + reg;
      P[(size_t)r * DOUT + col] = msg[mt][reg];
    }
  }
}

// ---------------- per-node epilogue ----------------
// mean-gather(P via CSR) + x@root + bias -> BN -> ReLU (+ bf16 copy)

template <int DIN, int DOUT>
__launch_bounds__(256)
__global__ void post_node(const float* P, const float* cnt, const int* noff,
                          const int* elist, const float* xin, const float* root,
                          const float* bias, const float* bg, const float* bb,
                          const float* bm, const float* bv, float* xout, short* xbf) {
  constexpr int NPB = 16;
  constexpr int OS = 256 / DOUT;   // 4/2/1 node-groups
  constexpr int NPT = NPB / OS;    // nodes per thread
  __shared__ float xs[NPB * DIN];
  __shared__ int offs[NPB], cnts[NPB];
  int n0 = blockIdx.x * NPB;
  int t = threadIdx.x;
  int o = t % DOUT;
  int ng = t / DOUT;
  if (t < NPB) {
    int n = n0 + t;
    offs[t] = (n < NN) ? noff[n] : 0;
    cnts[t] = (n < NN) ? (int)cnt[n] : 0;
  }
  for (int idx = t; idx < NPB * DIN; idx += 256) {
    int n = n0 + idx / DIN;
    xs[idx] = (n < NN) ? xin[(size_t)n * DIN + idx % DIN] : 0.f;
  }
  __syncthreads();
  float acc[NPT];
#pragma unroll
  for (int q = 0; q < NPT; ++q) acc[q] = 0.f;
  for (int i = 0; i < DIN; ++i) {
    float rv = root[(size_t)i * DOUT + o];
#pragma unroll
    for (int q = 0; q < NPT; ++q) acc[q] += xs[(ng + q * OS) * DIN + i] * rv;
  }
  float bi = bias[o];
  float scale = bg[o] * rsqrtf(bv[o] + 1e-5f);
  float mo = bm[o], bo = bb[o];
#pragma unroll
  for (int q = 0; q < NPT; ++q) {
    int nn = ng + q * OS;
    int n = n0 + nn;
    if (n >= NN) continue;
    int off = offs[nn], c = cnts[nn];
    float s = 0.f;
    for (int j = 0; j < c; ++j) {
      int e = elist[off + j];
      s += P[(size_t)e * DOUT + o];
    }
    float accv = s / fmaxf((float)c, 1.f) + bi + acc[q];
    float v = (accv - mo) * scale + bo;
    v = v > 0.f ? v : 0.f;
    xout[(size_t)n * DOUT + o] = v;
    if (xbf) xbf[(size_t)n * DOUT + o] = f2bf(v);
  }
}

// ---------------- finish: offsets + pool + node_embedding + final MLP ----------------

__global__ void finish(const float* gcnt, const int* atom, const float* x3,
                       const float* mw, const float* mb, float* out) {
  __shared__ float red[256];
  __shared__ float hnew[256];
  int g = blockIdx.x, t = threadIdx.x;
  red[t] = (t < NG && t < g) ? gcnt[t] : 0.f;  // exclusive prefix via reduce
  __syncthreads();
#pragma unroll
  for (int d = 128; d > 0; d >>= 1) {
    if (t < d) red[t] += red[t + d];
    __syncthreads();
  }
  int st = (int)red[0];
  int cn = (int)gcnt[g];
  int id = st + atom[g];
  id = id < 0 ? 0 : (id > NN - 1 ? NN - 1 : id);  // JAX gather clamp
  float s = 0.f;
  for (int n = st; n < st + cn; ++n) s += x3[(size_t)n * 256 + t];
  float ge = s / fmaxf((float)cn, 1.f);
  float ne = x3[(size_t)id * 256 + t];
  out[40000 + g * 256 + t] = ne;  // node_embedding output
  hnew[t] = 0.5f * ge + ne;
  __syncthreads();
  if (t < 200) {
    float a = mb[t];
#pragma unroll 8
    for (int oo = 0; oo < 256; ++oo) a += hnew[oo] * mw[(size_t)oo * 200 + t];
    out[g * 200 + t] = a;
  }
}

// ---------------- host side ----------------

template <int DIN_DATA, int DIN_PAD, int DOUT, int NSPLIT, int NKPE>
static void run_layer(void* const* d_in, int l, const int* srcI,
                      const short* xbf_in, const float* xin_f32, float* xout,
                      short* xbf_out, float* Pbuf, const float* cnt, const int* noff,
                      const int* elist, const short* ht, const short* Bp,
                      hipStream_t stream) {
  int base = 5 + (l - 1) * 10;
  const float* root = (const float*)d_in[base + 4];
  const float* bias = (const float*)d_in[base + 5];
  const float* bg = (const float*)d_in[base + 6];
  const float* bb = (const float*)d_in[base + 7];
  const float* bm = (const float*)d_in[base + 8];
  const float* bv = (const float*)d_in[base + 9];

  fused_gemm<DIN_PAD, DOUT, NSPLIT, NKPE>
      <<<dim3(MBLK, NSPLIT), 512, 0, stream>>>(xbf_in, ht, Bp, srcI, Pbuf);
  post_node<DIN_DATA, DOUT><<<(NN + 15) / 16, 256, 0, stream>>>(
      Pbuf, cnt, noff, elist, xin_f32, root, bias, bg, bb, bm, bv, xout, xbf_out);
}

extern "C" void kernel_launch(void* const* d_in, const int* in_sizes, int n_in,
                              void* d_out, int out_size, void* d_ws, size_t ws_size,
                              hipStream_t stream) {
  (void)in_sizes; (void)n_in; (void)out_size; (void)ws_size;
  const float* x0 = (const float*)d_in[0];
  const float* ea = (const float*)d_in[1];
  const int* eidx = (const int*)d_in[2];
  const int* batch = (const int*)d_in[3];
  const int* atom = (const int*)d_in[4];
  const float* mw = (const float*)d_in[35];
  const float* mb = (const float*)d_in[36];
  const int* srcI = eidx;
  const int* dstI = eidx + NE;
  float* out = (float*)d_out;

  char* p = (char*)d_ws;
  auto alloc = [&](size_t bytes) {
    char* r = p;
    p += (bytes + 255) & ~size_t(255);
    return r;
  };
  float* xA = (float*)alloc((size_t)NN * 256 * 4);
  float* xB = (float*)alloc((size_t)NN * 256 * 4);
  float* Pbuf = (float*)alloc((size_t)EROWS * 256 * 4);
  float* cnt = (float*)alloc(NN * 4);
  int* noff = (int*)alloc(NN * 4);
  int* fill = (int*)alloc(NN * 4);
  int* elist = (int*)alloc(NE * 4);
  float* gcnt = (float*)alloc(NG * 4);
  short* ht1 = (short*)alloc((size_t)NKP * EROWS * 2);
  short* ht2 = (short*)alloc((size_t)NKP * EROWS * 2);
  short* ht3 = (short*)alloc((size_t)NKP * EROWS * 2);
  short* Bp1 = (short*)alloc((size_t)NKP * 32 * 64 * 2);
  short* Bp2 = (short*)alloc((size_t)NKP * 64 * 128 * 2);
  short* Bp3 = (short*)alloc((size_t)NKP * 128 * 256 * 2);
  short* xbf0 = (short*)alloc((size_t)NN * 32 * 2);
  short* xbfA = (short*)alloc((size_t)NN * 64 * 2);
  short* xbfB = (short*)alloc((size_t)NN * 128 * 2);

  hipMemsetAsync(cnt, 0, NN * 4, stream);
  hipMemsetAsync(gcnt, 0, NG * 4, stream);
  prep<<<(NN * 32 + 255) / 256, 256, 0, stream>>>(dstI, batch, x0, cnt, gcnt, xbf0);
  node_scan<<<1, 1024, 0, stream>>>(cnt, noff, fill);
  csr_fill<<<(NE + 255) / 256, 256, 0, stream>>>(dstI, noff, fill, elist);
  edge_mlp_all<<<dim3((EROWS + 255) / 256, NKP, 3), 256, 0, stream>>>(
      ea, (const float*)d_in[5], (const float*)d_in[6],
      (const float*)d_in[15], (const float*)d_in[16],
      (const float*)d_in[25], (const float*)d_in[26], ht1, ht2, ht3);
  build_B_all<<<(BCH1 + BCH2 + BCH3 + 255) / 256, 256, 0, stream>>>(
      (const float*)d_in[7], (const float*)d_in[8],
      (const float*)d_in[17], (const float*)d_in[18],
      (const float*)d_in[27], (const float*)d_in[28], Bp1, Bp2, Bp3);

  run_layer<15, 32, 64, 1, 36>(d_in, 1, srcI, xbf0, x0, xA, xbfA, Pbuf, cnt,
                               noff, elist, ht1, Bp1, stream);
  run_layer<64, 64, 128, 2, 34>(d_in, 2, srcI, xbfA, xA, xB, xbfB, Pbuf, cnt,
                                noff, elist, ht2, Bp2, stream);
  run_layer<128, 128, 256, 4, 33>(d_in, 3, srcI, xbfB, xB, xA, (short*)nullptr,
                                  Pbuf, cnt, noff, elist, ht3, Bp3, stream);

  finish<<<NG, 256, 0, stream>>>(gcnt, atom, xA, mw, mb, out);
}

// Round 7
// 271.503 us; speedup vs baseline: 1.6976x; 1.1173x over previous
//
#include <hip/hip_runtime.h>
#include <stdint.h>

#define DEVINL __device__ __forceinline__

typedef __attribute__((ext_vector_type(8))) __bf16 bf16x8;
typedef __attribute__((ext_vector_type(8))) short s16x8;
typedef __attribute__((ext_vector_type(4))) float f32x4;

constexpr int NN = 5000;   // nodes
constexpr int NE = 10000;  // edges
constexpr int NG = 200;    // graphs
constexpr int BM = 64;                     // rows per GEMM block
constexpr int MBLK = (NE + BM - 1) / BM;   // 158 edge blocks
constexpr int EROWS = MBLK * BM;           // 10112
constexpr int SBLK = (NN + BM - 1) / BM;   // 79 self blocks
constexpr int SROWS = SBLK * BM;           // 5056
constexpr int NKP = 36;                    // built k rows (34 real: 32 + b2 + root)
constexpr int PHKT = 4;                    // kt per pipeline phase

DEVINL short f2bf(float f) {  // RNE fp32->bf16
  union { float f; unsigned u; } v; v.f = f;
  unsigned u = v.u + 0x7fffu + ((v.u >> 16) & 1u);
  return (short)(u >> 16);
}

DEVINL void gload16(const void* g, void* l) {
  __builtin_amdgcn_global_load_lds(
      (const __attribute__((address_space(1))) void*)g,
      (__attribute__((address_space(3))) void*)l, 16, 0, 0);
}

// ---------------- prep / CSR ----------------

__global__ void prep(const int* dst, const int* batch, const float* x0,
                     float* cnt, float* gcnt, short* xbf0) {
  int idx = blockIdx.x * 256 + threadIdx.x;
  if (idx < NE) atomicAdd(&cnt[dst[idx]], 1.0f);
  if (idx < NN) atomicAdd(&gcnt[batch[idx]], 1.0f);
  if (idx < NN * 32) {
    int n = idx >> 5, i = idx & 31;
    xbf0[idx] = (i < 15) ? f2bf(x0[n * 15 + i]) : (short)0;
  }
}

__global__ void node_scan(const float* cnt, int* noff, int* fill) {
  __shared__ int s[1024];
  __shared__ int carry;
  int t = threadIdx.x;
  if (t == 0) carry = 0;
  __syncthreads();
  for (int c0 = 0; c0 < NN; c0 += 1024) {
    int i = c0 + t;
    int v = (i < NN) ? (int)cnt[i] : 0;
    s[t] = v;
    __syncthreads();
    for (int d = 1; d < 1024; d <<= 1) {
      int u = (t >= d) ? s[t - d] : 0;
      __syncthreads();
      s[t] += u;
      __syncthreads();
    }
    if (i < NN) { noff[i] = carry + s[t] - v; fill[i] = 0; }
    __syncthreads();
    if (t == 0) carry += s[1023];
    __syncthreads();
  }
}

__global__ void csr_fill(const int* dst, const int* noff, int* fill, int* elist) {
  int e = blockIdx.x * 256 + threadIdx.x;
  if (e < NE) {
    int n = dst[e];
    int p = noff[n] + atomicAdd(&fill[n], 1);
    elist[p] = e;
  }
}

// ---------------- edge MLP (all 3 layers, transposed bf16 out) ----------------
// ht[k][e]: k<32 = relu(ea@w1+b1), k==32 = 1 (b2 row), k>=33 = 0 (root row is
// used only by self blocks, which bypass ht).

__global__ void edge_mlp_all(const float* ea,
                             const float* w1a, const float* b1a,
                             const float* w1b, const float* b1b,
                             const float* w1c, const float* b1c,
                             short* hta, short* htb, short* htc) {
  int L = blockIdx.z;
  const float* w1 = (L == 0) ? w1a : (L == 1) ? w1b : w1c;
  const float* b1 = (L == 0) ? b1a : (L == 1) ? b1b : b1c;
  short* ht = (L == 0) ? hta : (L == 1) ? htb : htc;
  __shared__ float w1s[3];
  __shared__ float b1s;
  int t = threadIdx.x;
  int k = blockIdx.y;
  if (t < 3 && k < 32) w1s[t] = w1[t * 32 + k];
  if (t == 0 && k < 32) b1s = b1[k];
  __syncthreads();
  int e = blockIdx.x * 256 + t;
  if (e >= EROWS) return;
  float v = 0.f;
  if (e < NE) {
    if (k < 32) {
      float a = b1s + ea[e * 3] * w1s[0] + ea[e * 3 + 1] * w1s[1] +
                ea[e * 3 + 2] * w1s[2];
      v = a > 0.f ? a : 0.f;
    } else if (k == 32) {
      v = 1.0f;
    }
  }
  ht[(size_t)k * EROWS + e] = f2bf(v);
}

// ---------------- B panels (all 3 layers) ----------------
// Bp[kt][n][kk] bf16, 16B chunks XOR-swizzled by ((n>>1)&3).
// kap = kt*32+kk = k*DIN_PAD+i; k<32 = w2, k==32 = b2, k==33 = root, else pad.

template <int DIN_DATA, int DIN_PAD, int DOUT>
DEVINL void buildB_one(int idx, const float* w2, const float* b2,
                       const float* root, short* Bp) {
  int cc = idx & 3;
  int n = (idx >> 2) % DOUT;
  int kt = (idx >> 2) / DOUT;
  int kap0 = kt * 32 + cc * 8;
  s16x8 v;
#pragma unroll
  for (int j = 0; j < 8; ++j) {
    int kap = kap0 + j;
    int k = kap / DIN_PAD, i = kap % DIN_PAD;
    float val = 0.f;
    if (i < DIN_DATA && k <= 33)
      val = (k < 32) ? w2[(size_t)(k * DIN_DATA + i) * DOUT + n]
                     : (k == 32) ? b2[(size_t)i * DOUT + n]
                                 : root[(size_t)i * DOUT + n];
    v[j] = f2bf(val);
  }
  int swz = cc ^ ((n >> 1) & 3);
  *(s16x8*)((char*)Bp + (size_t)kt * DOUT * 64 + n * 64 + swz * 16) = v;
}

constexpr int BCH1 = (NKP * 32 / 8) * 64;    // 9216
constexpr int BCH2 = (NKP * 64 / 8) * 128;   // 36864
constexpr int BCH3 = (NKP * 128 / 8) * 256;  // 147456

__global__ void build_B_all(const float* w2a, const float* b2a, const float* ra,
                            const float* w2b, const float* b2b, const float* rb,
                            const float* w2c, const float* b2c, const float* rc,
                            short* Bp1, short* Bp2, short* Bp3) {
  int idx = blockIdx.x * 256 + threadIdx.x;
  if (idx < BCH1) {
    buildB_one<15, 32, 64>(idx, w2a, b2a, ra, Bp1);
  } else if (idx < BCH1 + BCH2) {
    buildB_one<64, 64, 128>(idx - BCH1, w2b, b2b, rb, Bp2);
  } else if (idx < BCH1 + BCH2 + BCH3) {
    buildB_one<128, 128, 256>(idx - BCH1 - BCH2, w2c, b2c, rc, Bp3);
  }
}

// ---------------- fused gather + rank-structured GEMM ----------------
// Edge blocks (bx < MBLK):   P[e][o]        = sum_k ht[k][e] * (x[src[e]]@B_k)[o]
// Self blocks (bx >= MBLK):  P[EROWS+n][o]  = (x[n] @ B_33)[o] = (x[n]@root)[o]
// Counted-vmcnt phase pipeline (edge path): prefetch crosses barriers.

template <int DIN_PAD, int DOUT, int NSPLIT, int NKPE>
__launch_bounds__(512)
__global__ void fused_gemm(const short* xbf, const short* ht, const short* Bp,
                           const int* srcI, float* Pout) {
  constexpr int NI = DIN_PAD / 32;        // K-steps per k
  constexpr int ROWB = DIN_PAD * 2;       // bytes per xg row
  constexpr int CHPR = ROWB / 16;         // 16B chunks per row (4/8/16)
  constexpr int CHLOG = (CHPR == 4) ? 2 : (CHPR == 8) ? 3 : 4;
  constexpr int SWZM = (CHPR >= 8) ? 7 : 3;
  constexpr int DOUT_L = DOUT / NSPLIT;   // 64 cols per block
  constexpr int MT = 2;                   // wave covers 32 rows (2M x 4N waves)
  constexpr int KT_TOTAL = NKPE * NI;
  constexpr int NPH = KT_TOTAL / PHKT;
  static_assert(KT_TOTAL % PHKT == 0, "phase align");
  static_assert(PHKT % NI == 0 || NI % PHKT == 0, "k align");
  constexpr int PHB = PHKT * DOUT_L * 64; // 16 KB per phase buffer
  constexpr int CPK = DOUT_L * 4;         // 16B chunks per kt slice (256)
  constexpr int CH = PHKT * CPK;          // 1024 chunks per stage = 2/thread
  constexpr int XGB = BM * ROWB;
  constexpr int SMB = (XGB > 2 * PHB) ? XGB : 2 * PHB;

  __shared__ __align__(16) char smem[SMB];       // union: xg, then B dbuf
  __shared__ __align__(16) short hs[NKPE * BM];  // hs[k][r]
  __shared__ int src_s[BM];

  const int t = threadIdx.x, lane = t & 63, w = t >> 6;
  const int wm = w >> 2, wn = w & 3;
  const bool isSelf = (blockIdx.x >= MBLK);
  const int m0 = (isSelf ? (blockIdx.x - MBLK) : blockIdx.x) * BM;
  const int bn0 = blockIdx.y * DOUT_L;
  if (t < BM) {
    int r = m0 + t;
    src_s[t] = isSelf ? ((r < NN) ? r : 0) : ((r < NE) ? srcI[r] : 0);
  }
  __syncthreads();

  // ---- gather xg (LDS linear dest, swizzle folded into per-lane source) ----
  constexpr int XCH = BM * CHPR;  // 256/512/1024
#pragma unroll
  for (int rd = 0; rd < (XCH + 511) / 512; ++rd) {
    int L = rd * 512 + t;
    if (XCH % 512 == 0 || L < XCH) {
      int r = L >> CHLOG, pch = L & (CHPR - 1);
      int j = pch ^ (r & SWZM);
      gload16((const char*)xbf + (size_t)src_s[r] * ROWB + j * 16,
              (char*)smem + (size_t)L * 16);
    }
  }
  // ---- stage hs[k][0..BM) = ht[k][m0..m0+BM) (edge blocks only) ----
  if (!isSelf && t < NKPE * (BM / 8)) {
    int kl = t >> 3, c = t & 7;
    gload16((const char*)ht + ((size_t)kl * EROWS + m0) * 2 + c * 16,
            (char*)hs + (size_t)t * 16);
  }
  __syncthreads();  // full drain: xg + hs resident

  // ---- hoist A fragments; afterwards xg LDS is dead (reused for B dbuf) ----
  bf16x8 afr[NI][MT];
#pragma unroll
  for (int ii = 0; ii < NI; ++ii)
#pragma unroll
    for (int mt = 0; mt < MT; ++mt) {
      int r = wm * 32 + mt * 16 + (lane & 15);
      int c = ii * 4 + (lane >> 4);
      int pos = c ^ (r & SWZM);
      afr[ii][mt] = *(const bf16x8*)((const char*)smem + r * ROWB + pos * 16);
    }
  asm volatile("s_waitcnt lgkmcnt(0)" ::: "memory");
  __builtin_amdgcn_sched_barrier(0);
  __builtin_amdgcn_s_barrier();  // all waves: afr read done before overwrite

  const char* Bg = (const char*)Bp + (size_t)bn0 * 64;

  f32x4 msg[MT], part[MT];
#pragma unroll
  for (int mt = 0; mt < MT; ++mt)
#pragma unroll
    for (int i = 0; i < 4; ++i) { msg[mt][i] = 0.f; part[mt][i] = 0.f; }

  if (isSelf) {
    // ---- single K-chunk: kt in [33*NI, 34*NI), h == 1, no rescale ----
    constexpr int KT0 = 33 * NI;
    constexpr int CHS = NI * CPK;  // 256/512/1024 chunks
#pragma unroll
    for (int cc = 0; cc < (CHS + 511) / 512; ++cc) {
      int idx = cc * 512 + t;
      if (CHS % 512 == 0 || idx < CHS) {
        int ktl = idx / CPK, win = idx % CPK;
        gload16(Bg + (size_t)(KT0 + ktl) * (DOUT * 64) + (size_t)win * 16,
                (char*)smem + (size_t)idx * 16);
      }
    }
    asm volatile("s_waitcnt vmcnt(0)" ::: "memory");
    __builtin_amdgcn_s_barrier();
    __builtin_amdgcn_sched_barrier(0);
#pragma unroll
    for (int j = 0; j < NI; ++j) {
      bf16x8 bfr;
      {
        int n = wn * 16 + (lane & 15);
        int cch = (lane >> 4) ^ ((n >> 1) & 3);
        bfr = *(const bf16x8*)((const char*)smem + j * (DOUT_L * 64) + n * 64 +
                               cch * 16);
      }
#pragma unroll
      for (int mt = 0; mt < MT; ++mt)
        msg[mt] = __builtin_amdgcn_mfma_f32_16x16x32_bf16(afr[j][mt], bfr,
                                                          msg[mt], 0, 0, 0);
    }
    float* P = Pout + (size_t)(EROWS + m0) * DOUT + bn0;
#pragma unroll
    for (int mt = 0; mt < MT; ++mt) {
      int col = wn * 16 + (lane & 15);
#pragma unroll
      for (int reg = 0; reg < 4; ++reg) {
        int r = wm * 32 + mt * 16 + (lane >> 4) * 4 + reg;
        P[(size_t)r * DOUT + col] = msg[mt][reg];
      }
    }
    return;
  }

  // ---- edge main loop: counted-vmcnt phase pipeline ----
  auto stageB = [&](int ph, int buf) {
    char* dstB = (char*)smem + buf * PHB;
#pragma unroll
    for (int cc = 0; cc < CH / 512; ++cc) {
      int idx = cc * 512 + t;
      int ktl = idx / CPK;
      int win = idx % CPK;
      gload16(Bg + (size_t)(ph * PHKT + ktl) * (DOUT * 64) + (size_t)win * 16,
              dstB + (size_t)idx * 16);
    }
  };

  stageB(0, 0);  // 2 loads in flight
  int cur = 0;
  for (int ph = 0; ph < NPH; ++ph) {
    if (ph + 1 < NPH) {
      stageB(ph + 1, cur ^ 1);                          // +2 loads
      asm volatile("s_waitcnt vmcnt(2)" ::: "memory");  // wait older 2
    } else {
      asm volatile("s_waitcnt vmcnt(0)" ::: "memory");
    }
    __builtin_amdgcn_s_barrier();
    __builtin_amdgcn_sched_barrier(0);
#pragma unroll
    for (int j = 0; j < PHKT; ++j) {
      const int kt = ph * PHKT + j;
      bf16x8 bfr;
      {
        int n = wn * 16 + (lane & 15);
        int cch = (lane >> 4) ^ ((n >> 1) & 3);
        bfr = *(const bf16x8*)((const char*)smem + cur * PHB +
                               j * (DOUT_L * 64) + n * 64 + cch * 16);
      }
#pragma unroll
      for (int mt = 0; mt < MT; ++mt)
        part[mt] = __builtin_amdgcn_mfma_f32_16x16x32_bf16(
            afr[j % NI][mt], bfr, part[mt], 0, 0, 0);
      if ((j % NI) == NI - 1) {  // k boundary: rescale by h[r,k]
        int kl = kt / NI;
#pragma unroll
        for (int mt = 0; mt < MT; ++mt) {
          int rb = wm * 32 + mt * 16 + (lane >> 4) * 4;
          ushort4 hv = *(const ushort4*)((const char*)hs + (size_t)(kl * BM + rb) * 2);
          float h0, h1, h2, h3;
          { union { unsigned u; float f; } c;
            c.u = (unsigned)hv.x << 16; h0 = c.f;
            c.u = (unsigned)hv.y << 16; h1 = c.f;
            c.u = (unsigned)hv.z << 16; h2 = c.f;
            c.u = (unsigned)hv.w << 16; h3 = c.f; }
          msg[mt][0] += h0 * part[mt][0];
          msg[mt][1] += h1 * part[mt][1];
          msg[mt][2] += h2 * part[mt][2];
          msg[mt][3] += h3 * part[mt][3];
#pragma unroll
          for (int i = 0; i < 4; ++i) part[mt][i] = 0.f;
        }
      }
    }
    __builtin_amdgcn_sched_barrier(0);
    __builtin_amdgcn_s_barrier();  // reads done before next overwrite
    cur ^= 1;
  }
  // ---- epilogue: plain stores ----
  float* P = Pout + (size_t)m0 * DOUT + bn0;
#pragma unroll
  for (int mt = 0; mt < MT; ++mt) {
    int col = wn * 16 + (lane & 15);
#pragma unroll
    for (int reg = 0; reg < 4; ++reg) {
      int r = wm * 32 + mt * 16 + (lane >> 4) * 4 + reg;
      P[(size_t)r * DOUT + col] = msg[mt][reg];
    }
  }
}

// ---------------- per-node epilogue ----------------
// out = mean-gather(P via CSR) + P_self + bias -> BN -> ReLU (+ bf16 copy)

template <int DOUT>
__launch_bounds__(256)
__global__ void post_node(const float* P, const float* cnt, const int* noff,
                          const int* elist, const float* bias, const float* bg,
                          const float* bb, const float* bm, const float* bv,
                          float* xout, short* xbf) {
  constexpr int NPB = 8;
  constexpr int OS = 256 / DOUT;   // 4/2/1 node-groups
  constexpr int NPT = NPB / OS;    // nodes per thread
  __shared__ int offs[NPB], cnts[NPB];
  int n0 = blockIdx.x * NPB;
  int t = threadIdx.x;
  int o = t % DOUT;
  int ng = t / DOUT;
  if (t < NPB) {
    int n = n0 + t;
    offs[t] = (n < NN) ? noff[n] : 0;
    cnts[t] = (n < NN) ? (int)cnt[n] : 0;
  }
  __syncthreads();
  float bi = bias[o];
  float scale = bg[o] * rsqrtf(bv[o] + 1e-5f);
  float mo = bm[o], bo = bb[o];
#pragma unroll
  for (int q = 0; q < NPT; ++q) {
    int nn = ng + q * OS;
    int n = n0 + nn;
    if (n >= NN) continue;
    int off = offs[nn], c = cnts[nn];
    float s = 0.f;
    for (int j = 0; j < c; ++j) {
      int e = elist[off + j];
      s += P[(size_t)e * DOUT + o];
    }
    float selfv = P[(size_t)(EROWS + n) * DOUT + o];
    float accv = s / fmaxf((float)c, 1.f) + selfv + bi;
    float v = (accv - mo) * scale + bo;
    v = v > 0.f ? v : 0.f;
    if (xout) xout[(size_t)n * DOUT + o] = v;
    if (xbf) xbf[(size_t)n * DOUT + o] = f2bf(v);
  }
}

// ---------------- finish: offsets + pool + node_embedding + final MLP ----------------

__global__ void finish(const float* gcnt, const int* atom, const float* x3,
                       const float* mw, const float* mb, float* out) {
  __shared__ float red[256];
  __shared__ float hnew[256];
  int g = blockIdx.x, t = threadIdx.x;
  red[t] = (t < NG && t < g) ? gcnt[t] : 0.f;  // exclusive prefix via reduce
  __syncthreads();
#pragma unroll
  for (int d = 128; d > 0; d >>= 1) {
    if (t < d) red[t] += red[t + d];
    __syncthreads();
  }
  int st = (int)red[0];
  int cn = (int)gcnt[g];
  int id = st + atom[g];
  id = id < 0 ? 0 : (id > NN - 1 ? NN - 1 : id);  // JAX gather clamp
  float s = 0.f;
  for (int n = st; n < st + cn; ++n) s += x3[(size_t)n * 256 + t];
  float ge = s / fmaxf((float)cn, 1.f);
  float ne = x3[(size_t)id * 256 + t];
  out[40000 + g * 256 + t] = ne;  // node_embedding output
  hnew[t] = 0.5f * ge + ne;
  __syncthreads();
  if (t < 200) {
    float a = mb[t];
#pragma unroll 8
    for (int oo = 0; oo < 256; ++oo) a += hnew[oo] * mw[(size_t)oo * 200 + t];
    out[g * 200 + t] = a;
  }
}

// ---------------- host side ----------------

template <int DIN_PAD, int DOUT, int NSPLIT, int NKPE>
static void run_layer(void* const* d_in, int l, const int* srcI,
                      const short* xbf_in, float* xout_f32, short* xbf_out,
                      float* Pbuf, const float* cnt, const int* noff,
                      const int* elist, const short* ht, const short* Bp,
                      hipStream_t stream) {
  int base = 5 + (l - 1) * 10;
  const float* bias = (const float*)d_in[base + 5];
  const float* bg = (const float*)d_in[base + 6];
  const float* bb = (const float*)d_in[base + 7];
  const float* bm = (const float*)d_in[base + 8];
  const float* bv = (const float*)d_in[base + 9];

  fused_gemm<DIN_PAD, DOUT, NSPLIT, NKPE>
      <<<dim3(MBLK + SBLK, NSPLIT), 512, 0, stream>>>(xbf_in, ht, Bp, srcI, Pbuf);
  post_node<DOUT><<<(NN + 7) / 8, 256, 0, stream>>>(
      Pbuf, cnt, noff, elist, bias, bg, bb, bm, bv, xout_f32, xbf_out);
}

extern "C" void kernel_launch(void* const* d_in, const int* in_sizes, int n_in,
                              void* d_out, int out_size, void* d_ws, size_t ws_size,
                              hipStream_t stream) {
  (void)in_sizes; (void)n_in; (void)out_size; (void)ws_size;
  const float* x0 = (const float*)d_in[0];
  const float* ea = (const float*)d_in[1];
  const int* eidx = (const int*)d_in[2];
  const int* batch = (const int*)d_in[3];
  const int* atom = (const int*)d_in[4];
  const float* mw = (const float*)d_in[35];
  const float* mb = (const float*)d_in[36];
  const int* srcI = eidx;
  const int* dstI = eidx + NE;
  float* out = (float*)d_out;

  char* p = (char*)d_ws;
  auto alloc = [&](size_t bytes) {
    char* r = p;
    p += (bytes + 255) & ~size_t(255);
    return r;
  };
  float* xA = (float*)alloc((size_t)NN * 256 * 4);         // layer-3 f32 out
  float* Pbuf = (float*)alloc((size_t)(EROWS + SROWS) * 256 * 4);
  float* cnt = (float*)alloc(NN * 4);
  int* noff = (int*)alloc(NN * 4);
  int* fill = (int*)alloc(NN * 4);
  int* elist = (int*)alloc(NE * 4);
  float* gcnt = (float*)alloc(NG * 4);
  short* ht1 = (short*)alloc((size_t)NKP * EROWS * 2);
  short* ht2 = (short*)alloc((size_t)NKP * EROWS * 2);
  short* ht3 = (short*)alloc((size_t)NKP * EROWS * 2);
  short* Bp1 = (short*)alloc((size_t)NKP * 32 * 64 * 2);
  short* Bp2 = (short*)alloc((size_t)NKP * 64 * 128 * 2);
  short* Bp3 = (short*)alloc((size_t)NKP * 128 * 256 * 2);
  short* xbf0 = (short*)alloc((size_t)NN * 32 * 2);
  short* xbfA = (short*)alloc((size_t)NN * 64 * 2);
  short* xbfB = (short*)alloc((size_t)NN * 128 * 2);

  hipMemsetAsync(cnt, 0, NN * 4, stream);
  hipMemsetAsync(gcnt, 0, NG * 4, stream);
  prep<<<(NN * 32 + 255) / 256, 256, 0, stream>>>(dstI, batch, x0, cnt, gcnt, xbf0);
  node_scan<<<1, 1024, 0, stream>>>(cnt, noff, fill);
  csr_fill<<<(NE + 255) / 256, 256, 0, stream>>>(dstI, noff, fill, elist);
  edge_mlp_all<<<dim3((EROWS + 255) / 256, NKP, 3), 256, 0, stream>>>(
      ea, (const float*)d_in[5], (const float*)d_in[6],
      (const float*)d_in[15], (const float*)d_in[16],
      (const float*)d_in[25], (const float*)d_in[26], ht1, ht2, ht3);
  build_B_all<<<(BCH1 + BCH2 + BCH3 + 255) / 256, 256, 0, stream>>>(
      (const float*)d_in[7], (const float*)d_in[8], (const float*)d_in[9],
      (const float*)d_in[17], (const float*)d_in[18], (const float*)d_in[19],
      (const float*)d_in[27], (const float*)d_in[28], (const float*)d_in[29],
      Bp1, Bp2, Bp3);

  run_layer<32, 64, 1, 36>(d_in, 1, srcI, xbf0, (float*)nullptr, xbfA, Pbuf,
                           cnt, noff, elist, ht1, Bp1, stream);
  run_layer<64, 128, 2, 34>(d_in, 2, srcI, xbfA, (float*)nullptr, xbfB, Pbuf,
                            cnt, noff, elist, ht2, Bp2, stream);
  run_layer<128, 256, 4, 33>(d_in, 3, srcI, xbfB, xA, (short*)nullptr, Pbuf,
                             cnt, noff, elist, ht3, Bp3, stream);

  finish<<<NG, 256, 0, stream>>>(gcnt, atom, xA, mw, mb, out);
}

// Round 8
// 260.896 us; speedup vs baseline: 1.7666x; 1.0407x over previous
//
#include <hip/hip_runtime.h>
#include <stdint.h>

#define DEVINL __device__ __forceinline__

typedef __attribute__((ext_vector_type(8))) __bf16 bf16x8;
typedef __attribute__((ext_vector_type(8))) short s16x8;
typedef __attribute__((ext_vector_type(4))) float f32x4;

constexpr int NN = 5000;   // nodes
constexpr int NE = 10000;  // edges
constexpr int NG = 200;    // graphs
constexpr int BM = 64;                     // rows per GEMM block
constexpr int MBLK = (NE + BM - 1) / BM;   // 158 edge blocks
constexpr int EROWS = MBLK * BM;           // 10112
constexpr int SBLK = (NN + BM - 1) / BM;   // 79 self blocks
constexpr int SROWS = SBLK * BM;           // 5056
constexpr int NKP = 36;                    // built k rows (34 real: 32 + b2 + root)
constexpr int PHKT = 4;                    // kt per pipeline phase
constexpr int NBUF = 3;                    // B pipeline depth

DEVINL short f2bf(float f) {  // RNE fp32->bf16
  union { float f; unsigned u; } v; v.f = f;
  unsigned u = v.u + 0x7fffu + ((v.u >> 16) & 1u);
  return (short)(u >> 16);
}

DEVINL void gload16(const void* g, void* l) {
  __builtin_amdgcn_global_load_lds(
      (const __attribute__((address_space(1))) void*)g,
      (__attribute__((address_space(3))) void*)l, 16, 0, 0);
}

// ---------------- B panel builder (shared) ----------------
// Bp[kt][n][kk] bf16, 16B chunks XOR-swizzled by ((n>>1)&3).
// kap = kt*32+kk = k*DIN_PAD+i; k<32 = w2, k==32 = b2, k==33 = root, else pad.

template <int DIN_DATA, int DIN_PAD, int DOUT>
DEVINL void buildB_one(int idx, const float* w2, const float* b2,
                       const float* root, short* Bp) {
  int cc = idx & 3;
  int n = (idx >> 2) % DOUT;
  int kt = (idx >> 2) / DOUT;
  int kap0 = kt * 32 + cc * 8;
  s16x8 v;
#pragma unroll
  for (int j = 0; j < 8; ++j) {
    int kap = kap0 + j;
    int k = kap / DIN_PAD, i = kap % DIN_PAD;
    float val = 0.f;
    if (i < DIN_DATA && k <= 33)
      val = (k < 32) ? w2[(size_t)(k * DIN_DATA + i) * DOUT + n]
                     : (k == 32) ? b2[(size_t)i * DOUT + n]
                                 : root[(size_t)i * DOUT + n];
    v[j] = f2bf(val);
  }
  int swz = cc ^ ((n >> 1) & 3);
  *(s16x8*)((char*)Bp + (size_t)kt * DOUT * 64 + n * 64 + swz * 16) = v;
}

constexpr int BCH1 = (NKP * 32 / 8) * 64;    // 9216
constexpr int BCH2 = (NKP * 64 / 8) * 128;   // 36864
constexpr int BCH3 = (NKP * 128 / 8) * 256;  // 147456
constexpr int EMB = (EROWS + 255) / 256;     // 40 blocks per layer (edge MLP)
constexpr int PREPB = (NN * 32 + 255) / 256; // 625
constexpr int BLDB = (BCH1 + BCH2 + BCH3 + 255) / 256;  // 756

// ---------------- setup: edge-MLP(x3) + prep + build_B, one launch ----------------
// ht[k][e]: k<32 = relu(ea@w1+b1), k==32 = 1 (b2 row), k>32 = 0.

__global__ void setup(const float* ea, const int* dst, const int* batch,
                      const float* x0,
                      const float* w1a, const float* b1a,
                      const float* w1b, const float* b1b,
                      const float* w1c, const float* b1c,
                      const float* w2a, const float* b2a, const float* ra,
                      const float* w2b, const float* b2b, const float* rb,
                      const float* w2c, const float* b2c, const float* rc,
                      short* hta, short* htb, short* htc,
                      short* Bp1, short* Bp2, short* Bp3,
                      float* cnt, float* gcnt, short* xbf0) {
  int b = blockIdx.x, t = threadIdx.x;
  if (b < 3 * EMB) {
    int L = b / EMB, eb = b % EMB;
    const float* w1 = (L == 0) ? w1a : (L == 1) ? w1b : w1c;
    const float* b1 = (L == 0) ? b1a : (L == 1) ? b1b : b1c;
    short* ht = (L == 0) ? hta : (L == 1) ? htb : htc;
    int e = eb * 256 + t;
    if (e >= EROWS) return;
    bool ve = e < NE;
    float a0 = 0, a1 = 0, a2 = 0;
    if (ve) { a0 = ea[e * 3]; a1 = ea[e * 3 + 1]; a2 = ea[e * 3 + 2]; }
    for (int k = 0; k < NKP; ++k) {
      float v = 0.f;
      if (ve) {
        if (k < 32) {
          float x = b1[k] + a0 * w1[k] + a1 * w1[32 + k] + a2 * w1[64 + k];
          v = x > 0.f ? x : 0.f;
        } else if (k == 32) {
          v = 1.0f;
        }
      }
      ht[(size_t)k * EROWS + e] = f2bf(v);
    }
  } else if (b < 3 * EMB + PREPB) {
    int idx = (b - 3 * EMB) * 256 + t;
    if (idx < NE) atomicAdd(&cnt[dst[idx]], 1.0f);
    if (idx < NN) atomicAdd(&gcnt[batch[idx]], 1.0f);
    if (idx < NN * 32) {
      int n = idx >> 5, i = idx & 31;
      xbf0[idx] = (i < 15) ? f2bf(x0[n * 15 + i]) : (short)0;
    }
  } else {
    int idx = (b - 3 * EMB - PREPB) * 256 + t;
    if (idx < BCH1) {
      buildB_one<15, 32, 64>(idx, w2a, b2a, ra, Bp1);
    } else if (idx < BCH1 + BCH2) {
      buildB_one<64, 64, 128>(idx - BCH1, w2b, b2b, rb, Bp2);
    } else if (idx < BCH1 + BCH2 + BCH3) {
      buildB_one<128, 128, 256>(idx - BCH1 - BCH2, w2c, b2c, rc, Bp3);
    }
  }
}

// ---------------- node scan (one pass) + csr fill ----------------

__global__ void node_scan(const float* cnt, int* noff, int* fill) {
  constexpr int PT = (NN + 1023) / 1024;  // 5 nodes per thread
  __shared__ int s[1024];
  int t = threadIdx.x;
  int loc[PT];
  int sum = 0;
#pragma unroll
  for (int q = 0; q < PT; ++q) {
    int i = t * PT + q;
    loc[q] = sum;
    sum += (i < NN) ? (int)cnt[i] : 0;
  }
  s[t] = sum;
  __syncthreads();
  for (int d = 1; d < 1024; d <<= 1) {
    int u = (t >= d) ? s[t - d] : 0;
    __syncthreads();
    s[t] += u;
    __syncthreads();
  }
  int base = s[t] - sum;  // exclusive prefix of this thread's chunk
#pragma unroll
  for (int q = 0; q < PT; ++q) {
    int i = t * PT + q;
    if (i < NN) { noff[i] = base + loc[q]; fill[i] = 0; }
  }
}

__global__ void csr_fill(const int* dst, const int* noff, int* fill, int* elist) {
  int e = blockIdx.x * 256 + threadIdx.x;
  if (e < NE) {
    int n = dst[e];
    int p = noff[n] + atomicAdd(&fill[n], 1);
    elist[p] = e;
  }
}

// ---------------- fused gather + rank-structured GEMM ----------------
// Edge blocks (bx < MBLK):   P[e][o]        = sum_k ht[k][e] * (x[src[e]]@B_k)[o]
// Self blocks (bx >= MBLK):  P[EROWS+n][o]  = (x[n] @ B_33)[o] = (x[n]@root)[o]
// 3-deep counted-vmcnt pipeline: 3 B phase-buffers, steady wait vmcnt(4),
// ~2 phase-times of latency cover (works even at ~1 block/CU).

template <int DIN_PAD, int DOUT, int NSPLIT, int NKPE>
__launch_bounds__(512)
__global__ void fused_gemm(const short* xbf, const short* ht, const short* Bp,
                           const int* srcI, float* Pout) {
  constexpr int NI = DIN_PAD / 32;        // K-steps per k
  constexpr int ROWB = DIN_PAD * 2;       // bytes per xg row
  constexpr int CHPR = ROWB / 16;         // 16B chunks per row (4/8/16)
  constexpr int CHLOG = (CHPR == 4) ? 2 : (CHPR == 8) ? 3 : 4;
  constexpr int SWZM = (CHPR >= 8) ? 7 : 3;
  constexpr int DOUT_L = DOUT / NSPLIT;   // 64 cols per block
  constexpr int MT = 2;                   // wave covers 32 rows (2M x 4N waves)
  constexpr int KT_TOTAL = NKPE * NI;
  constexpr int NPH = KT_TOTAL / PHKT;
  static_assert(KT_TOTAL % PHKT == 0, "phase align");
  static_assert(PHKT % NI == 0 || NI % PHKT == 0, "k align");
  constexpr int PHB = PHKT * DOUT_L * 64; // 16 KB per phase buffer
  constexpr int CPK = DOUT_L * 4;         // 16B chunks per kt slice (256)
  constexpr int CH = PHKT * CPK;          // 1024 chunks per stage = 2/thread
  constexpr int XGB = BM * ROWB;
  constexpr int SMB = (XGB > NBUF * PHB) ? XGB : NBUF * PHB;

  __shared__ __align__(16) char smem[SMB];       // union: xg, then B 3-buf
  __shared__ __align__(16) short hs[NKPE * BM];  // hs[k][r]
  __shared__ int src_s[BM];

  const int t = threadIdx.x, lane = t & 63, w = t >> 6;
  const int wm = w >> 2, wn = w & 3;
  const bool isSelf = (blockIdx.x >= MBLK);
  const int m0 = (isSelf ? (blockIdx.x - MBLK) : blockIdx.x) * BM;
  const int bn0 = blockIdx.y * DOUT_L;
  if (t < BM) {
    int r = m0 + t;
    src_s[t] = isSelf ? ((r < NN) ? r : 0) : ((r < NE) ? srcI[r] : 0);
  }
  __syncthreads();

  // ---- gather xg (LDS linear dest, swizzle folded into per-lane source) ----
  constexpr int XCH = BM * CHPR;  // 256/512/1024
#pragma unroll
  for (int rd = 0; rd < (XCH + 511) / 512; ++rd) {
    int L = rd * 512 + t;
    if (XCH % 512 == 0 || L < XCH) {
      int r = L >> CHLOG, pch = L & (CHPR - 1);
      int j = pch ^ (r & SWZM);
      gload16((const char*)xbf + (size_t)src_s[r] * ROWB + j * 16,
              (char*)smem + (size_t)L * 16);
    }
  }
  // ---- stage hs[k][0..BM) = ht[k][m0..m0+BM) (edge blocks only) ----
  if (!isSelf && t < NKPE * (BM / 8)) {
    int kl = t >> 3, c = t & 7;
    gload16((const char*)ht + ((size_t)kl * EROWS + m0) * 2 + c * 16,
            (char*)hs + (size_t)t * 16);
  }
  __syncthreads();  // full drain: xg + hs resident

  // ---- hoist A fragments; afterwards xg LDS is dead (reused for B bufs) ----
  bf16x8 afr[NI][MT];
#pragma unroll
  for (int ii = 0; ii < NI; ++ii)
#pragma unroll
    for (int mt = 0; mt < MT; ++mt) {
      int r = wm * 32 + mt * 16 + (lane & 15);
      int c = ii * 4 + (lane >> 4);
      int pos = c ^ (r & SWZM);
      afr[ii][mt] = *(const bf16x8*)((const char*)smem + r * ROWB + pos * 16);
    }
  asm volatile("s_waitcnt lgkmcnt(0)" ::: "memory");
  __builtin_amdgcn_sched_barrier(0);
  __builtin_amdgcn_s_barrier();  // all waves: afr read done before overwrite

  const char* Bg = (const char*)Bp + (size_t)bn0 * 64;

  f32x4 msg[MT], part[MT];
#pragma unroll
  for (int mt = 0; mt < MT; ++mt)
#pragma unroll
    for (int i = 0; i < 4; ++i) { msg[mt][i] = 0.f; part[mt][i] = 0.f; }

  if (isSelf) {
    // ---- single K-chunk: kt in [33*NI, 34*NI), h == 1, no rescale ----
    constexpr int KT0 = 33 * NI;
    constexpr int CHS = NI * CPK;
#pragma unroll
    for (int cc = 0; cc < (CHS + 511) / 512; ++cc) {
      int idx = cc * 512 + t;
      if (CHS % 512 == 0 || idx < CHS) {
        int ktl = idx / CPK, win = idx % CPK;
        gload16(Bg + (size_t)(KT0 + ktl) * (DOUT * 64) + (size_t)win * 16,
                (char*)smem + (size_t)idx * 16);
      }
    }
    asm volatile("s_waitcnt vmcnt(0)" ::: "memory");
    __builtin_amdgcn_s_barrier();
    __builtin_amdgcn_sched_barrier(0);
#pragma unroll
    for (int j = 0; j < NI; ++j) {
      bf16x8 bfr;
      {
        int n = wn * 16 + (lane & 15);
        int cch = (lane >> 4) ^ ((n >> 1) & 3);
        bfr = *(const bf16x8*)((const char*)smem + j * (DOUT_L * 64) + n * 64 +
                               cch * 16);
      }
#pragma unroll
      for (int mt = 0; mt < MT; ++mt)
        msg[mt] = __builtin_amdgcn_mfma_f32_16x16x32_bf16(afr[j][mt], bfr,
                                                          msg[mt], 0, 0, 0);
    }
    float* P = Pout + (size_t)(EROWS + m0) * DOUT + bn0;
#pragma unroll
    for (int mt = 0; mt < MT; ++mt) {
      int col = wn * 16 + (lane & 15);
#pragma unroll
      for (int reg = 0; reg < 4; ++reg) {
        int r = wm * 32 + mt * 16 + (lane >> 4) * 4 + reg;
        P[(size_t)r * DOUT + col] = msg[mt][reg];
      }
    }
    return;
  }

  // ---- edge main loop: 3-deep counted-vmcnt pipeline ----
  auto stageB = [&](int ph, int buf) {
    char* dstB = (char*)smem + buf * PHB;
#pragma unroll
    for (int cc = 0; cc < CH / 512; ++cc) {
      int idx = cc * 512 + t;
      int ktl = idx / CPK;
      int win = idx % CPK;
      gload16(Bg + (size_t)(ph * PHKT + ktl) * (DOUT * 64) + (size_t)win * 16,
              dstB + (size_t)idx * 16);
    }
  };

  stageB(0, 0);
  if (NPH > 1) stageB(1, 1);
  if (NPH > 2) stageB(2, 2);
  for (int ph = 0; ph < NPH; ++ph) {
    // drain stage(ph): 2 loads per stage, up to 2 younger stages in flight
    if (ph + 2 < NPH) {
      asm volatile("s_waitcnt vmcnt(4)" ::: "memory");
    } else if (ph + 1 < NPH) {
      asm volatile("s_waitcnt vmcnt(2)" ::: "memory");
    } else {
      asm volatile("s_waitcnt vmcnt(0)" ::: "memory");
    }
    __builtin_amdgcn_s_barrier();
    __builtin_amdgcn_sched_barrier(0);
    const char* buf = (const char*)smem + (ph % NBUF) * PHB;
#pragma unroll
    for (int j = 0; j < PHKT; ++j) {
      const int kt = ph * PHKT + j;
      bf16x8 bfr;
      {
        int n = wn * 16 + (lane & 15);
        int cch = (lane >> 4) ^ ((n >> 1) & 3);
        bfr = *(const bf16x8*)(buf + j * (DOUT_L * 64) + n * 64 + cch * 16);
      }
#pragma unroll
      for (int mt = 0; mt < MT; ++mt)
        part[mt] = __builtin_amdgcn_mfma_f32_16x16x32_bf16(
            afr[j % NI][mt], bfr, part[mt], 0, 0, 0);
      if ((j % NI) == NI - 1) {  // k boundary: rescale by h[r,k]
        int kl = kt / NI;
#pragma unroll
        for (int mt = 0; mt < MT; ++mt) {
          int rb = wm * 32 + mt * 16 + (lane >> 4) * 4;
          ushort4 hv = *(const ushort4*)((const char*)hs + (size_t)(kl * BM + rb) * 2);
          float h0, h1, h2, h3;
          { union { unsigned u; float f; } c;
            c.u = (unsigned)hv.x << 16; h0 = c.f;
            c.u = (unsigned)hv.y << 16; h1 = c.f;
            c.u = (unsigned)hv.z << 16; h2 = c.f;
            c.u = (unsigned)hv.w << 16; h3 = c.f; }
          msg[mt][0] += h0 * part[mt][0];
          msg[mt][1] += h1 * part[mt][1];
          msg[mt][2] += h2 * part[mt][2];
          msg[mt][3] += h3 * part[mt][3];
#pragma unroll
          for (int i = 0; i < 4; ++i) part[mt][i] = 0.f;
        }
      }
    }
    __builtin_amdgcn_sched_barrier(0);
    __builtin_amdgcn_s_barrier();  // reads of buf(ph%3) done before re-stage
    if (ph + NBUF < NPH) stageB(ph + NBUF, (ph + NBUF) % NBUF);
  }
  // ---- epilogue: plain stores ----
  float* P = Pout + (size_t)m0 * DOUT + bn0;
#pragma unroll
  for (int mt = 0; mt < MT; ++mt) {
    int col = wn * 16 + (lane & 15);
#pragma unroll
    for (int reg = 0; reg < 4; ++reg) {
      int r = wm * 32 + mt * 16 + (lane >> 4) * 4 + reg;
      P[(size_t)r * DOUT + col] = msg[mt][reg];
    }
  }
}

// ---------------- per-node epilogue ----------------
// out = mean-gather(P via CSR) + P_self + bias -> BN -> ReLU (+ bf16 copy)

template <int DOUT>
__launch_bounds__(256)
__global__ void post_node(const float* P, const float* cnt, const int* noff,
                          const int* elist, const float* bias, const float* bg,
                          const float* bb, const float* bm, const float* bv,
                          float* xout, short* xbf) {
  constexpr int NPB = 8;
  constexpr int OS = 256 / DOUT;   // 4/2/1 node-groups
  constexpr int NPT = NPB / OS;    // nodes per thread
  __shared__ int offs[NPB], cnts[NPB];
  int n0 = blockIdx.x * NPB;
  int t = threadIdx.x;
  int o = t % DOUT;
  int ng = t / DOUT;
  if (t < NPB) {
    int n = n0 + t;
    offs[t] = (n < NN) ? noff[n] : 0;
    cnts[t] = (n < NN) ? (int)cnt[n] : 0;
  }
  __syncthreads();
  float bi = bias[o];
  float scale = bg[o] * rsqrtf(bv[o] + 1e-5f);
  float mo = bm[o], bo = bb[o];
#pragma unroll
  for (int q = 0; q < NPT; ++q) {
    int nn = ng + q * OS;
    int n = n0 + nn;
    if (n >= NN) continue;
    int off = offs[nn], c = cnts[nn];
    float s = 0.f;
    for (int j = 0; j < c; ++j) {
      int e = elist[off + j];
      s += P[(size_t)e * DOUT + o];
    }
    float selfv = P[(size_t)(EROWS + n) * DOUT + o];
    float accv = s / fmaxf((float)c, 1.f) + selfv + bi;
    float v = (accv - mo) * scale + bo;
    v = v > 0.f ? v : 0.f;
    if (xout) xout[(size_t)n * DOUT + o] = v;
    if (xbf) xbf[(size_t)n * DOUT + o] = f2bf(v);
  }
}

// ---------------- finish: offsets + pool + node_embedding + final MLP ----------------

__global__ void finish(const float* gcnt, const int* atom, const float* x3,
                       const float* mw, const float* mb, float* out) {
  __shared__ float red[256];
  __shared__ float hnew[256];
  int g = blockIdx.x, t = threadIdx.x;
  red[t] = (t < NG && t < g) ? gcnt[t] : 0.f;  // exclusive prefix via reduce
  __syncthreads();
#pragma unroll
  for (int d = 128; d > 0; d >>= 1) {
    if (t < d) red[t] += red[t + d];
    __syncthreads();
  }
  int st = (int)red[0];
  int cn = (int)gcnt[g];
  int id = st + atom[g];
  id = id < 0 ? 0 : (id > NN - 1 ? NN - 1 : id);  // JAX gather clamp
  float s = 0.f;
  for (int n = st; n < st + cn; ++n) s += x3[(size_t)n * 256 + t];
  float ge = s / fmaxf((float)cn, 1.f);
  float ne = x3[(size_t)id * 256 + t];
  out[40000 + g * 256 + t] = ne;  // node_embedding output
  hnew[t] = 0.5f * ge + ne;
  __syncthreads();
  if (t < 200) {
    float a = mb[t];
#pragma unroll 8
    for (int oo = 0; oo < 256; ++oo) a += hnew[oo] * mw[(size_t)oo * 200 + t];
    out[g * 200 + t] = a;
  }
}

// ---------------- host side ----------------

template <int DIN_PAD, int DOUT, int NSPLIT, int NKPE>
static void run_layer(void* const* d_in, int l, const int* srcI,
                      const short* xbf_in, float* xout_f32, short* xbf_out,
                      float* Pbuf, const float* cnt, const int* noff,
                      const int* elist, const short* ht, const short* Bp,
                      hipStream_t stream) {
  int base = 5 + (l - 1) * 10;
  const float* bias = (const float*)d_in[base + 5];
  const float* bg = (const float*)d_in[base + 6];
  const float* bb = (const float*)d_in[base + 7];
  const float* bm = (const float*)d_in[base + 8];
  const float* bv = (const float*)d_in[base + 9];

  fused_gemm<DIN_PAD, DOUT, NSPLIT, NKPE>
      <<<dim3(MBLK + SBLK, NSPLIT), 512, 0, stream>>>(xbf_in, ht, Bp, srcI, Pbuf);
  post_node<DOUT><<<(NN + 7) / 8, 256, 0, stream>>>(
      Pbuf, cnt, noff, elist, bias, bg, bb, bm, bv, xout_f32, xbf_out);
}

extern "C" void kernel_launch(void* const* d_in, const int* in_sizes, int n_in,
                              void* d_out, int out_size, void* d_ws, size_t ws_size,
                              hipStream_t stream) {
  (void)in_sizes; (void)n_in; (void)out_size; (void)ws_size;
  const float* x0 = (const float*)d_in[0];
  const float* ea = (const float*)d_in[1];
  const int* eidx = (const int*)d_in[2];
  const int* batch = (const int*)d_in[3];
  const int* atom = (const int*)d_in[4];
  const float* mw = (const float*)d_in[35];
  const float* mb = (const float*)d_in[36];
  const int* srcI = eidx;
  const int* dstI = eidx + NE;
  float* out = (float*)d_out;

  char* p = (char*)d_ws;
  auto alloc = [&](size_t bytes) {
    char* r = p;
    p += (bytes + 255) & ~size_t(255);
    return r;
  };
  float* xA = (float*)alloc((size_t)NN * 256 * 4);         // layer-3 f32 out
  float* Pbuf = (float*)alloc((size_t)(EROWS + SROWS) * 256 * 4);
  float* cnt = (float*)alloc(NN * 4);
  int* noff = (int*)alloc(NN * 4);
  int* fill = (int*)alloc(NN * 4);
  int* elist = (int*)alloc(NE * 4);
  float* gcnt = (float*)alloc(NG * 4);
  short* ht1 = (short*)alloc((size_t)NKP * EROWS * 2);
  short* ht2 = (short*)alloc((size_t)NKP * EROWS * 2);
  short* ht3 = (short*)alloc((size_t)NKP * EROWS * 2);
  short* Bp1 = (short*)alloc((size_t)NKP * 32 * 64 * 2);
  short* Bp2 = (short*)alloc((size_t)NKP * 64 * 128 * 2);
  short* Bp3 = (short*)alloc((size_t)NKP * 128 * 256 * 2);
  short* xbf0 = (short*)alloc((size_t)NN * 32 * 2);
  short* xbfA = (short*)alloc((size_t)NN * 64 * 2);
  short* xbfB = (short*)alloc((size_t)NN * 128 * 2);

  hipMemsetAsync(cnt, 0, NN * 4, stream);
  hipMemsetAsync(gcnt, 0, NG * 4, stream);
  setup<<<3 * EMB + PREPB + BLDB, 256, 0, stream>>>(
      ea, dstI, batch, x0,
      (const float*)d_in[5], (const float*)d_in[6],
      (const float*)d_in[15], (const float*)d_in[16],
      (const float*)d_in[25], (const float*)d_in[26],
      (const float*)d_in[7], (const float*)d_in[8], (const float*)d_in[9],
      (const float*)d_in[17], (const float*)d_in[18], (const float*)d_in[19],
      (const float*)d_in[27], (const float*)d_in[28], (const float*)d_in[29],
      ht1, ht2, ht3, Bp1, Bp2, Bp3, cnt, gcnt, xbf0);
  node_scan<<<1, 1024, 0, stream>>>(cnt, noff, fill);
  csr_fill<<<(NE + 255) / 256, 256, 0, stream>>>(dstI, noff, fill, elist);

  run_layer<32, 64, 1, 36>(d_in, 1, srcI, xbf0, (float*)nullptr, xbfA, Pbuf,
                           cnt, noff, elist, ht1, Bp1, stream);
  run_layer<64, 128, 2, 34>(d_in, 2, srcI, xbfA, (float*)nullptr, xbfB, Pbuf,
                            cnt, noff, elist, ht2, Bp2, stream);
  run_layer<128, 256, 4, 33>(d_in, 3, srcI, xbfB, xA, (short*)nullptr, Pbuf,
                             cnt, noff, elist, ht3, Bp3, stream);

  finish<<<NG, 256, 0, stream>>>(gcnt, atom, xA, mw, mb, out);
}

// Round 9
// 258.680 us; speedup vs baseline: 1.7817x; 1.0086x over previous
//
#include <hip/hip_runtime.h>
#include <stdint.h>

#define DEVINL __device__ __forceinline__

typedef __attribute__((ext_vector_type(8))) __bf16 bf16x8;
typedef __attribute__((ext_vector_type(8))) short s16x8;
typedef __attribute__((ext_vector_type(4))) float f32x4;

constexpr int NN = 5000;   // nodes
constexpr int NE = 10000;  // edges
constexpr int NG = 200;    // graphs
constexpr int EROWS = 10112;               // padded edge rows (mult of 128)
constexpr int SROWSMX = 5120;              // padded self rows (mult of 128)
constexpr int NKP = 36;                    // built k rows (34 real: 32 + b2 + root)
constexpr int PHKT = 4;                    // kt per pipeline phase
constexpr int NBUF = 3;                    // B pipeline depth

DEVINL short f2bf(float f) {  // RNE fp32->bf16
  union { float f; unsigned u; } v; v.f = f;
  unsigned u = v.u + 0x7fffu + ((v.u >> 16) & 1u);
  return (short)(u >> 16);
}

DEVINL void gload16(const void* g, void* l) {
  __builtin_amdgcn_global_load_lds(
      (const __attribute__((address_space(1))) void*)g,
      (__attribute__((address_space(3))) void*)l, 16, 0, 0);
}

// ---------------- B panel builder ----------------
// Bp[kt][n][kk] bf16, 16B chunks XOR-swizzled by ((n>>1)&3).
// kap = kt*32+kk = k*DIN_PAD+i; k<32 = w2, k==32 = b2, k==33 = root, else pad.

template <int DIN_DATA, int DIN_PAD, int DOUT>
DEVINL void buildB_one(int idx, const float* w2, const float* b2,
                       const float* root, short* Bp) {
  int cc = idx & 3;
  int n = (idx >> 2) % DOUT;
  int kt = (idx >> 2) / DOUT;
  int kap0 = kt * 32 + cc * 8;
  s16x8 v;
#pragma unroll
  for (int j = 0; j < 8; ++j) {
    int kap = kap0 + j;
    int k = kap / DIN_PAD, i = kap % DIN_PAD;
    float val = 0.f;
    if (i < DIN_DATA && k <= 33)
      val = (k < 32) ? w2[(size_t)(k * DIN_DATA + i) * DOUT + n]
                     : (k == 32) ? b2[(size_t)i * DOUT + n]
                                 : root[(size_t)i * DOUT + n];
    v[j] = f2bf(val);
  }
  int swz = cc ^ ((n >> 1) & 3);
  *(s16x8*)((char*)Bp + (size_t)kt * DOUT * 64 + n * 64 + swz * 16) = v;
}

constexpr int BCH1 = (NKP * 32 / 8) * 64;    // 9216
constexpr int BCH2 = (NKP * 64 / 8) * 128;   // 36864
constexpr int BCH3 = (NKP * 128 / 8) * 256;  // 147456
constexpr int EMB = (EROWS + 1023) / 1024;          // 10 blocks/layer
constexpr int CASTB = (NN * 32 + 1023) / 1024;      // 157
constexpr int BLDB = (BCH1 + BCH2 + BCH3 + 1023) / 1024;  // 190
constexpr int SETUPB = 3 * EMB + CASTB + BLDB + 1;  // +1 = CSR scan block

// ---------------- setup: edge-MLP(x3) + cast + build_B + CSR, one launch ----
// ht[k][e] f32: k<32 = relu(ea@w1+b1), k==32 = 1 (b2 row), k>32 = 0.
// Last block: builds cnt/gcnt in LDS, scans -> noff, fills elist.

__global__ __launch_bounds__(1024) void setup(
    const float* ea, const int* dst, const int* batch, const float* x0,
    const float* w1a, const float* b1a, const float* w1b, const float* b1b,
    const float* w1c, const float* b1c,
    const float* w2a, const float* b2a, const float* ra,
    const float* w2b, const float* b2b, const float* rb,
    const float* w2c, const float* b2c, const float* rc,
    float* hta, float* htb, float* htc,
    short* Bp1, short* Bp2, short* Bp3,
    short* xbf0, int* noff, int* elist, float* gcnt) {
  int b = blockIdx.x, t = threadIdx.x;
  if (b < 3 * EMB) {
    int L = b / EMB, eb = b % EMB;
    const float* w1 = (L == 0) ? w1a : (L == 1) ? w1b : w1c;
    const float* b1 = (L == 0) ? b1a : (L == 1) ? b1b : b1c;
    float* ht = (L == 0) ? hta : (L == 1) ? htb : htc;
    int e = eb * 1024 + t;
    if (e >= EROWS) return;
    bool ve = e < NE;
    float a0 = 0, a1 = 0, a2 = 0;
    if (ve) { a0 = ea[e * 3]; a1 = ea[e * 3 + 1]; a2 = ea[e * 3 + 2]; }
    for (int k = 0; k < NKP; ++k) {
      float v = 0.f;
      if (ve) {
        if (k < 32) {
          float x = b1[k] + a0 * w1[k] + a1 * w1[32 + k] + a2 * w1[64 + k];
          v = x > 0.f ? x : 0.f;
        } else if (k == 32) {
          v = 1.0f;
        }
      }
      ht[(size_t)k * EROWS + e] = v;
    }
  } else if (b < 3 * EMB + CASTB) {
    int idx = (b - 3 * EMB) * 1024 + t;
    if (idx < NN * 32) {
      int n = idx >> 5, i = idx & 31;
      xbf0[idx] = (i < 15) ? f2bf(x0[n * 15 + i]) : (short)0;
    }
  } else if (b < 3 * EMB + CASTB + BLDB) {
    int idx = (b - 3 * EMB - CASTB) * 1024 + t;
    if (idx < BCH1) {
      buildB_one<15, 32, 64>(idx, w2a, b2a, ra, Bp1);
    } else if (idx < BCH1 + BCH2) {
      buildB_one<64, 64, 128>(idx - BCH1, w2b, b2b, rb, Bp2);
    } else if (idx < BCH1 + BCH2 + BCH3) {
      buildB_one<128, 128, 256>(idx - BCH1 - BCH2, w2c, b2c, rc, Bp3);
    }
  } else {
    // ---- CSR block: cnt/gcnt in LDS, scan, fill ----
    __shared__ int cntL[NN];
    __shared__ int sS[1024];
    __shared__ int gcntL[NG];
    for (int i = t; i < NN; i += 1024) cntL[i] = 0;
    if (t < NG) gcntL[t] = 0;
    __syncthreads();
    for (int e = t; e < NE; e += 1024) atomicAdd(&cntL[dst[e]], 1);
    for (int i = t; i < NN; i += 1024) atomicAdd(&gcntL[batch[i]], 1);
    __syncthreads();
    constexpr int PT = (NN + 1023) / 1024;  // 5
    int loc[PT];
    int sum = 0;
#pragma unroll
    for (int q = 0; q < PT; ++q) {
      int i = t * PT + q;
      loc[q] = sum;
      sum += (i < NN) ? cntL[i] : 0;
    }
    sS[t] = sum;
    __syncthreads();
    for (int d = 1; d < 1024; d <<= 1) {
      int u = (t >= d) ? sS[t - d] : 0;
      __syncthreads();
      sS[t] += u;
      __syncthreads();
    }
    int base = sS[t] - sum;
#pragma unroll
    for (int q = 0; q < PT; ++q) {
      int i = t * PT + q;
      if (i < NN) {
        int v = base + loc[q];
        noff[i] = v;
        cntL[i] = v;  // reuse as fill pointer
      }
    }
    if (t < 16) noff[NN + t] = NE;           // sentinel pad
    if (t < NG) gcnt[t] = (float)gcntL[t];
    __syncthreads();
    for (int e = t; e < NE; e += 1024) {
      int n = dst[e];
      int p = atomicAdd(&cntL[n], 1);
      elist[p] = e;
    }
  }
}

// ---------------- fused gather + rank-structured GEMM ----------------
// Edge blocks (bx < MBLK):  P[e][o]       = sum_k ht[k][e] * (x[src[e]]@B_k)[o]
// Self blocks (bx >= MBLK): P[EROWS+n][o] = (x[n] @ B_33)[o] = (x[n]@root)[o]
// 3-deep counted-vmcnt pipeline; hs staged as f32 (no unpack in rescale).

template <int BMT, int DIN_PAD, int DOUT, int NSPLIT, int NKPE>
__launch_bounds__(512)
__global__ void fused_gemm(const short* xbf, const float* ht, const short* Bp,
                           const int* srcI, float* Pout) {
  constexpr int MBLK = (NE + BMT - 1) / BMT;
  constexpr int NI = DIN_PAD / 32;        // K-steps per k
  constexpr int ROWB = DIN_PAD * 2;       // bytes per xg row
  constexpr int CHPR = ROWB / 16;         // 16B chunks per row (4/8/16)
  constexpr int CHLOG = (CHPR == 4) ? 2 : (CHPR == 8) ? 3 : 4;
  constexpr int SWZM = (CHPR >= 8) ? 7 : 3;
  constexpr int DOUT_L = DOUT / NSPLIT;   // 64 cols per block
  constexpr int MT = BMT / 32;            // frags per wave-m (2M x 4N waves)
  constexpr int WROWS = MT * 16;          // rows per wave-m
  constexpr int KT_TOTAL = NKPE * NI;
  constexpr int NPH = KT_TOTAL / PHKT;
  static_assert(KT_TOTAL % PHKT == 0, "phase align");
  static_assert(PHKT % NI == 0 || NI % PHKT == 0, "k align");
  constexpr int PHB = PHKT * DOUT_L * 64; // 16 KB per phase buffer
  constexpr int CPK = DOUT_L * 4;         // 16B chunks per kt slice (256)
  constexpr int CH = PHKT * CPK;          // 1024 chunks per stage = 2/thread
  constexpr int XGB = BMT * ROWB;
  constexpr int SMB = (XGB > NBUF * PHB) ? XGB : NBUF * PHB;

  __shared__ __align__(16) char smem[SMB];       // union: xg, then B bufs
  __shared__ __align__(16) float hs[NKPE * BMT]; // hs[k][r] f32
  __shared__ int src_s[BMT];

  const int t = threadIdx.x, lane = t & 63, w = t >> 6;
  const int wm = w >> 2, wn = w & 3;
  const bool isSelf = (blockIdx.x >= MBLK);
  const int m0 = (isSelf ? (blockIdx.x - MBLK) : blockIdx.x) * BMT;
  const int bn0 = blockIdx.y * DOUT_L;
  if (t < BMT) {
    int r = m0 + t;
    src_s[t] = isSelf ? ((r < NN) ? r : 0) : ((r < NE) ? srcI[r] : 0);
  }
  __syncthreads();

  // ---- gather xg (LDS linear dest, swizzle folded into per-lane source) ----
  constexpr int XCH = BMT * CHPR;
#pragma unroll
  for (int rd = 0; rd < (XCH + 511) / 512; ++rd) {
    int L = rd * 512 + t;
    if (XCH % 512 == 0 || L < XCH) {
      int r = L >> CHLOG, pch = L & (CHPR - 1);
      int j = pch ^ (r & SWZM);
      gload16((const char*)xbf + (size_t)src_s[r] * ROWB + j * 16,
              (char*)smem + (size_t)L * 16);
    }
  }
  // ---- stage hs f32: NKPE*BMT/4 16B chunks (edge blocks only) ----
  if (!isSelf) {
    constexpr int CHH = NKPE * BMT / 4;
    for (int idx = t; idx < CHH; idx += 512) {
      int kl = idx / (BMT / 4), c = idx % (BMT / 4);
      gload16((const char*)ht + ((size_t)kl * EROWS + m0 + c * 4) * 4,
              (char*)hs + (size_t)idx * 16);
    }
  }
  __syncthreads();  // full drain: xg + hs resident

  // ---- hoist A fragments; afterwards xg LDS is dead (reused for B bufs) ----
  bf16x8 afr[NI][MT];
#pragma unroll
  for (int ii = 0; ii < NI; ++ii)
#pragma unroll
    for (int mt = 0; mt < MT; ++mt) {
      int r = wm * WROWS + mt * 16 + (lane & 15);
      int c = ii * 4 + (lane >> 4);
      int pos = c ^ (r & SWZM);
      afr[ii][mt] = *(const bf16x8*)((const char*)smem + r * ROWB + pos * 16);
    }
  asm volatile("s_waitcnt lgkmcnt(0)" ::: "memory");
  __builtin_amdgcn_sched_barrier(0);
  __builtin_amdgcn_s_barrier();  // all waves: afr read done before overwrite

  const char* Bg = (const char*)Bp + (size_t)bn0 * 64;

  f32x4 msg[MT], part[MT];
#pragma unroll
  for (int mt = 0; mt < MT; ++mt)
#pragma unroll
    for (int i = 0; i < 4; ++i) { msg[mt][i] = 0.f; part[mt][i] = 0.f; }

  if (isSelf) {
    // ---- single K-chunk: kt in [33*NI, 34*NI), h == 1, no rescale ----
    constexpr int KT0 = 33 * NI;
    constexpr int CHS = NI * CPK;
#pragma unroll
    for (int cc = 0; cc < (CHS + 511) / 512; ++cc) {
      int idx = cc * 512 + t;
      if (CHS % 512 == 0 || idx < CHS) {
        int ktl = idx / CPK, win = idx % CPK;
        gload16(Bg + (size_t)(KT0 + ktl) * (DOUT * 64) + (size_t)win * 16,
                (char*)smem + (size_t)idx * 16);
      }
    }
    asm volatile("s_waitcnt vmcnt(0)" ::: "memory");
    __builtin_amdgcn_s_barrier();
    __builtin_amdgcn_sched_barrier(0);
#pragma unroll
    for (int j = 0; j < NI; ++j) {
      bf16x8 bfr;
      {
        int n = wn * 16 + (lane & 15);
        int cch = (lane >> 4) ^ ((n >> 1) & 3);
        bfr = *(const bf16x8*)((const char*)smem + j * (DOUT_L * 64) + n * 64 +
                               cch * 16);
      }
#pragma unroll
      for (int mt = 0; mt < MT; ++mt)
        msg[mt] = __builtin_amdgcn_mfma_f32_16x16x32_bf16(afr[j][mt], bfr,
                                                          msg[mt], 0, 0, 0);
    }
    float* P = Pout + (size_t)(EROWS + m0) * DOUT + bn0;
#pragma unroll
    for (int mt = 0; mt < MT; ++mt) {
      int col = wn * 16 + (lane & 15);
#pragma unroll
      for (int reg = 0; reg < 4; ++reg) {
        int r = wm * WROWS + mt * 16 + (lane >> 4) * 4 + reg;
        P[(size_t)r * DOUT + col] = msg[mt][reg];
      }
    }
    return;
  }

  // ---- edge main loop: 3-deep counted-vmcnt pipeline ----
  auto stageB = [&](int ph, int buf) {
    char* dstB = (char*)smem + buf * PHB;
#pragma unroll
    for (int cc = 0; cc < CH / 512; ++cc) {
      int idx = cc * 512 + t;
      int ktl = idx / CPK;
      int win = idx % CPK;
      gload16(Bg + (size_t)(ph * PHKT + ktl) * (DOUT * 64) + (size_t)win * 16,
              dstB + (size_t)idx * 16);
    }
  };

  stageB(0, 0);
  if (NPH > 1) stageB(1, 1);
  if (NPH > 2) stageB(2, 2);
  for (int ph = 0; ph < NPH; ++ph) {
    if (ph + 2 < NPH) {
      asm volatile("s_waitcnt vmcnt(4)" ::: "memory");
    } else if (ph + 1 < NPH) {
      asm volatile("s_waitcnt vmcnt(2)" ::: "memory");
    } else {
      asm volatile("s_waitcnt vmcnt(0)" ::: "memory");
    }
    __builtin_amdgcn_s_barrier();
    __builtin_amdgcn_sched_barrier(0);
    const char* buf = (const char*)smem + (ph % NBUF) * PHB;
#pragma unroll
    for (int j = 0; j < PHKT; ++j) {
      const int kt = ph * PHKT + j;
      bf16x8 bfr;
      {
        int n = wn * 16 + (lane & 15);
        int cch = (lane >> 4) ^ ((n >> 1) & 3);
        bfr = *(const bf16x8*)(buf + j * (DOUT_L * 64) + n * 64 + cch * 16);
      }
#pragma unroll
      for (int mt = 0; mt < MT; ++mt)
        part[mt] = __builtin_amdgcn_mfma_f32_16x16x32_bf16(
            afr[j % NI][mt], bfr, part[mt], 0, 0, 0);
      if ((j % NI) == NI - 1) {  // k boundary: rescale by h[r,k] (f32 hs)
        int kl = kt / NI;
#pragma unroll
        for (int mt = 0; mt < MT; ++mt) {
          int rb = wm * WROWS + mt * 16 + (lane >> 4) * 4;
          float4 hv = *(const float4*)(hs + (size_t)kl * BMT + rb);
          msg[mt][0] += hv.x * part[mt][0];
          msg[mt][1] += hv.y * part[mt][1];
          msg[mt][2] += hv.z * part[mt][2];
          msg[mt][3] += hv.w * part[mt][3];
#pragma unroll
          for (int i = 0; i < 4; ++i) part[mt][i] = 0.f;
        }
      }
    }
    __builtin_amdgcn_sched_barrier(0);
    __builtin_amdgcn_s_barrier();  // reads of buf(ph%3) done before re-stage
    if (ph + NBUF < NPH) stageB(ph + NBUF, (ph + NBUF) % NBUF);
  }
  // ---- epilogue: plain stores ----
  float* P = Pout + (size_t)m0 * DOUT + bn0;
#pragma unroll
  for (int mt = 0; mt < MT; ++mt) {
    int col = wn * 16 + (lane & 15);
#pragma unroll
    for (int reg = 0; reg < 4; ++reg) {
      int r = wm * WROWS + mt * 16 + (lane >> 4) * 4 + reg;
      P[(size_t)r * DOUT + col] = msg[mt][reg];
    }
  }
}

// ---------------- per-node epilogue ----------------
// out = mean-gather(P via CSR, LDS-staged elist range) + P_self + bias -> BN -> ReLU

template <int DOUT>
__launch_bounds__(256)
__global__ void post_node(const float* P, const int* noff, const int* elist,
                          const float* bias, const float* bg, const float* bb,
                          const float* bm, const float* bv, float* xout,
                          short* xbf) {
  constexpr int NPB = 8;
  constexpr int OS = 256 / DOUT;   // 4/2/1 node-groups
  constexpr int NPT = NPB / OS;    // nodes per thread
  __shared__ int offs[NPB + 1];
  __shared__ int es[256];
  int n0 = blockIdx.x * NPB;
  int t = threadIdx.x;
  if (t <= NPB) offs[t] = noff[n0 + t];  // sentinel-padded
  __syncthreads();
  int base = offs[0];
  int range = offs[NPB] - base;
  bool fit = (range <= 256);
  if (fit) {
    for (int i = t; i < range; i += 256) es[i] = elist[base + i];
  }
  __syncthreads();
  int o = t % DOUT, ng = t / DOUT;
  float bi = bias[o];
  float scale = bg[o] * rsqrtf(bv[o] + 1e-5f);
  float mo = bm[o], bo = bb[o];
#pragma unroll
  for (int q = 0; q < NPT; ++q) {
    int nn = ng + q * OS;
    int n = n0 + nn;
    if (n >= NN) continue;
    int off0 = offs[nn], c = offs[nn + 1] - off0;
    float s = 0.f;
    for (int j = 0; j < c; ++j) {
      int e = fit ? es[off0 - base + j] : elist[off0 + j];
      s += P[(size_t)e * DOUT + o];
    }
    float selfv = P[(size_t)(EROWS + n) * DOUT + o];
    float accv = s / fmaxf((float)c, 1.f) + selfv + bi;
    float v = (accv - mo) * scale + bo;
    v = v > 0.f ? v : 0.f;
    if (xout) xout[(size_t)n * DOUT + o] = v;
    if (xbf) xbf[(size_t)n * DOUT + o] = f2bf(v);
  }
}

// ---------------- finish: offsets + pool + node_embedding + final MLP ------

__global__ void finish(const float* gcnt, const int* atom, const float* x3,
                       const float* mw, const float* mb, float* out) {
  __shared__ float red[256];
  __shared__ float hnew[256];
  int g = blockIdx.x, t = threadIdx.x;
  red[t] = (t < NG && t < g) ? gcnt[t] : 0.f;  // exclusive prefix via reduce
  __syncthreads();
#pragma unroll
  for (int d = 128; d > 0; d >>= 1) {
    if (t < d) red[t] += red[t + d];
    __syncthreads();
  }
  int st = (int)red[0];
  int cn = (int)gcnt[g];
  int id = st + atom[g];
  id = id < 0 ? 0 : (id > NN - 1 ? NN - 1 : id);  // JAX gather clamp
  float s = 0.f;
  for (int n = st; n < st + cn; ++n) s += x3[(size_t)n * 256 + t];
  float ge = s / fmaxf((float)cn, 1.f);
  float ne = x3[(size_t)id * 256 + t];
  out[40000 + g * 256 + t] = ne;  // node_embedding output
  hnew[t] = 0.5f * ge + ne;
  __syncthreads();
  if (t < 200) {
    float a = mb[t];
#pragma unroll 8
    for (int oo = 0; oo < 256; ++oo) a += hnew[oo] * mw[(size_t)oo * 200 + t];
    out[g * 200 + t] = a;
  }
}

// ---------------- host side ----------------

template <int BMT, int DIN_PAD, int DOUT, int NSPLIT, int NKPE>
static void run_layer(void* const* d_in, int l, const int* srcI,
                      const short* xbf_in, float* xout_f32, short* xbf_out,
                      float* Pbuf, const int* noff, const int* elist,
                      const float* ht, const short* Bp, hipStream_t stream) {
  int base = 5 + (l - 1) * 10;
  const float* bias = (const float*)d_in[base + 5];
  const float* bg = (const float*)d_in[base + 6];
  const float* bb = (const float*)d_in[base + 7];
  const float* bm = (const float*)d_in[base + 8];
  const float* bv = (const float*)d_in[base + 9];

  constexpr int MBLK = (NE + BMT - 1) / BMT;
  constexpr int SBLK = (NN + BMT - 1) / BMT;
  fused_gemm<BMT, DIN_PAD, DOUT, NSPLIT, NKPE>
      <<<dim3(MBLK + SBLK, NSPLIT), 512, 0, stream>>>(xbf_in, ht, Bp, srcI, Pbuf);
  post_node<DOUT><<<(NN + 7) / 8, 256, 0, stream>>>(
      Pbuf, noff, elist, bias, bg, bb, bm, bv, xout_f32, xbf_out);
}

extern "C" void kernel_launch(void* const* d_in, const int* in_sizes, int n_in,
                              void* d_out, int out_size, void* d_ws, size_t ws_size,
                              hipStream_t stream) {
  (void)in_sizes; (void)n_in; (void)out_size; (void)ws_size;
  const float* x0 = (const float*)d_in[0];
  const float* ea = (const float*)d_in[1];
  const int* eidx = (const int*)d_in[2];
  const int* batch = (const int*)d_in[3];
  const int* atom = (const int*)d_in[4];
  const float* mw = (const float*)d_in[35];
  const float* mb = (const float*)d_in[36];
  const int* srcI = eidx;
  const int* dstI = eidx + NE;
  float* out = (float*)d_out;

  char* p = (char*)d_ws;
  auto alloc = [&](size_t bytes) {
    char* r = p;
    p += (bytes + 255) & ~size_t(255);
    return r;
  };
  float* xA = (float*)alloc((size_t)NN * 256 * 4);  // layer-3 f32 out
  float* Pbuf = (float*)alloc((size_t)(EROWS + SROWSMX) * 256 * 4);
  int* noff = (int*)alloc((NN + 16) * 4);
  int* elist = (int*)alloc(NE * 4);
  float* gcnt = (float*)alloc(NG * 4);
  float* ht1 = (float*)alloc((size_t)NKP * EROWS * 4);
  float* ht2 = (float*)alloc((size_t)NKP * EROWS * 4);
  float* ht3 = (float*)alloc((size_t)NKP * EROWS * 4);
  short* Bp1 = (short*)alloc((size_t)NKP * 32 * 64 * 2);
  short* Bp2 = (short*)alloc((size_t)NKP * 64 * 128 * 2);
  short* Bp3 = (short*)alloc((size_t)NKP * 128 * 256 * 2);
  short* xbf0 = (short*)alloc((size_t)NN * 32 * 2);
  short* xbfA = (short*)alloc((size_t)NN * 64 * 2);
  short* xbfB = (short*)alloc((size_t)NN * 128 * 2);

  setup<<<SETUPB, 1024, 0, stream>>>(
      ea, dstI, batch, x0,
      (const float*)d_in[5], (const float*)d_in[6],
      (const float*)d_in[15], (const float*)d_in[16],
      (const float*)d_in[25], (const float*)d_in[26],
      (const float*)d_in[7], (const float*)d_in[8], (const float*)d_in[9],
      (const float*)d_in[17], (const float*)d_in[18], (const float*)d_in[19],
      (const float*)d_in[27], (const float*)d_in[28], (const float*)d_in[29],
      ht1, ht2, ht3, Bp1, Bp2, Bp3, xbf0, noff, elist, gcnt);

  run_layer<64, 32, 64, 1, 36>(d_in, 1, srcI, xbf0, (float*)nullptr, xbfA, Pbuf,
                               noff, elist, ht1, Bp1, stream);
  run_layer<64, 64, 128, 2, 34>(d_in, 2, srcI, xbfA, (float*)nullptr, xbfB, Pbuf,
                                noff, elist, ht2, Bp2, stream);
  run_layer<128, 128, 256, 4, 33>(d_in, 3, srcI, xbfB, xA, (short*)nullptr, Pbuf,
                                  noff, elist, ht3, Bp3, stream);

  finish<<<NG, 256, 0, stream>>>(gcnt, atom, xA, mw, mb, out);
}